// Round 17
// baseline (961.756 us; speedup 1.0000x reference)
//
#include <hip/hip_runtime.h>
#include <math.h>

#define NEGV -1e10f

typedef __bf16 bf16x8 __attribute__((ext_vector_type(8)));
typedef float f32x4 __attribute__((ext_vector_type(4)));
typedef unsigned short ushort;
typedef unsigned int uint;

__device__ __forceinline__ float fast_tanh(float x) {
    float e = __expf(2.0f * x);
    return fmaf(-2.f, __builtin_amdgcn_rcpf(e + 1.f), 1.f);
}
__device__ __forceinline__ float fast_sig(float x) {
    return __builtin_amdgcn_rcpf(1.f + __expf(-x));
}
__device__ __forceinline__ ushort f2bf(float x) {
    unsigned int b = __float_as_uint(x);
    b += 0x7fffu + ((b >> 16) & 1u);   // RNE
    return (ushort)(b >> 16);
}
#if __has_builtin(__builtin_amdgcn_sdot4)
#define SDOT4(a, b, c) __builtin_amdgcn_sdot4((int)(a), (int)(b), (int)(c), false)
#else
__device__ __forceinline__ int SDOT4(int a, int b, int c) {
    #pragma unroll
    for (int k = 0; k < 4; k++) {
        int xa = (a >> (8 * k)) & 0xff; xa = (xa ^ 0x80) - 0x80;
        int xb = (b >> (8 * k)) & 0xff; xb = (xb ^ 0x80) - 0x80;
        c += xa * xb;
    }
    return c;
}
#endif
// VALU-pipe lane swaps within quads: quad_perm[1,0,3,2]=0xB1 (lane^1),
// quad_perm[2,3,0,1]=0x4E (lane^2)
__device__ __forceinline__ int dpp_xor1(int v) {
    return __builtin_amdgcn_update_dpp(0, v, 0xB1, 0xf, 0xf, true);
}
__device__ __forceinline__ int dpp_xor2(int v) {
    return __builtin_amdgcn_update_dpp(0, v, 0x4E, 0xf, 0xf, true);
}
// async 16B global -> LDS (dest = wave-uniform base + lane*16, src per-lane)
__device__ __forceinline__ void async16(void* l, const void* g) {
    __builtin_amdgcn_global_load_lds(
        (const __attribute__((address_space(1))) void*)g,
        (__attribute__((address_space(3))) void*)l,
        16, 0, 0);
}

// ---------------- dual fp32 -> bf16 cast (both n % 8 == 0) ----------------
__global__ __launch_bounds__(256) void cast2_bf16_kernel(
    const float* __restrict__ inA, const float* __restrict__ inB,
    ushort* __restrict__ outA, ushort* __restrict__ outB, int nA, int nB)
{
    int i = (blockIdx.x * 256 + threadIdx.x) * 8;
    const float* in;
    ushort* out;
    if (i < nA) { in = inA; out = outA; }
    else {
        i -= nA;
        if (i >= nB) return;
        in = inB; out = outB;
    }
    float4 a = *(const float4*)(in + i);
    float4 b = *(const float4*)(in + i + 4);
    uint4 o;
    o.x = (unsigned)f2bf(a.x) | ((unsigned)f2bf(a.y) << 16);
    o.y = (unsigned)f2bf(a.z) | ((unsigned)f2bf(a.w) << 16);
    o.z = (unsigned)f2bf(b.x) | ((unsigned)f2bf(b.y) << 16);
    o.w = (unsigned)f2bf(b.z) | ((unsigned)f2bf(b.w) << 16);
    *(uint4*)(out + i) = o;
}

// ============ prep_all: whh-int8 pack | bias concat | Bp_att | Bp_out | bias_pad ============
// blocks [0,8): per-mat int8 pack, LDS-staging layout (chunk-major, lane-consecutive):
//   dword j = g*16+jj of lane l -> frag8[mat*4096 + (j>>2)*256 + l*4 + (j&3)]
//   ksc[mat*256 + l*4 + g] = (amax/127)/127
// blocks [8,16): bias_all; [16,272): Bp_att rows; [272,400): Bp_out rows; 400: bias_pad
__global__ __launch_bounds__(256) void prep_all_kernel(
    const float* W0, const float* W1, const float* W2, const float* W3,
    const float* W4, const float* W5, const float* W6, const float* W7,
    uint* __restrict__ frag8, float* __restrict__ ksc,
    const float* s0, const float* s1, const float* s2, const float* s3,
    const float* s4, const float* s5, const float* s6, const float* s7,
    float* __restrict__ bias_all,
    const float* __restrict__ Watt_w, ushort* __restrict__ Bp_att,
    const float* __restrict__ out1_w, ushort* __restrict__ Bp_out,
    const float* __restrict__ Watt_b, float* __restrict__ bias_pad)
{
    const int bx = blockIdx.x, tid = threadIdx.x;
    if (bx < 8) {
        const float* Ws[8] = {W0, W1, W2, W3, W4, W5, W6, W7};
        const float* W = Ws[bx];
        int l = tid >> 2, g = tid & 3;
        const float* row = W + (size_t)(g * 64 + l) * 64;
        float amax = 0.f;
        for (int k = 0; k < 64; k++) amax = fmaxf(amax, fabsf(row[k]));
        float sw = fmaxf(amax, 1e-12f) / 127.f;
        float inv = 127.f / fmaxf(amax, 1e-12f);
        ksc[bx * 256 + l * 4 + g] = sw / 127.f;
        for (int jj = 0; jj < 16; jj++) {
            uint wd = 0;
            #pragma unroll
            for (int k = 0; k < 4; k++) {
                int q = __float2int_rn(row[4 * jj + k] * inv);
                q = max(-127, min(127, q));
                wd |= ((uint)(q & 0xff)) << (8 * k);
            }
            int j = g * 16 + jj;
            frag8[bx * 4096 + (j >> 2) * 256 + l * 4 + (j & 3)] = wd;
        }
    } else if (bx < 16) {
        const float* srcs[8] = {s0, s1, s2, s3, s4, s5, s6, s7};
        bias_all[(bx - 8) * 256 + tid] = srcs[bx - 8][tid];
    } else if (bx < 272) {
        int rowi = bx - 16;
        if (tid < 96) {
            float a = 0.f, b = 0.f;
            if (rowi < 132) {
                const float* s = Watt_w + (size_t)rowi * 140;
                if (2 * tid < 140) a = s[2 * tid];
                if (2 * tid + 1 < 140) b = s[2 * tid + 1];
            }
            ((uint*)(Bp_att + (size_t)rowi * 192))[tid] =
                (uint)f2bf(a) | ((uint)f2bf(b) << 16);
        }
    } else if (bx < 400) {
        int rowi = bx - 272;
        if (tid < 96) {
            const float* s = out1_w + (size_t)rowi * 524 + 384;
            float a = (2 * tid < 140) ? s[2 * tid] : 0.f;
            float b = (2 * tid + 1 < 140) ? s[2 * tid + 1] : 0.f;
            ((uint*)(Bp_out + (size_t)rowi * 192))[tid] =
                (uint)f2bf(a) | ((uint)f2bf(b) << 16);
        }
    } else {
        bias_pad[tid] = (tid < 132) ? Watt_b[tid] : 0.f;
    }
}

// =============== shared MFMA GEMM core: C = A[.,K]bf16 @ B[.,K]bf16^T (+bias) ===============
// mode 1: fp32 store, cols < Nstore. mode 2: bf16 store, scan-perm layout
// (col = dir*256+g*64+u -> dir*256 + u*4 + g), ldc elements.
__device__ __forceinline__ void gemm_core(
    const ushort* __restrict__ A, const ushort* __restrict__ B,
    const float* __restrict__ bias, void* __restrict__ C,
    int K, int ldc, int Nstore, int mode, int bm, int bn, ushort* lds)
{
    ushort* ldsA = lds;
    ushort* ldsB = lds + 8192;
    const int tid = threadIdx.x;
    const int wv = tid >> 6, ln = tid & 63;
    const int r15 = ln & 15, r4 = ln >> 4;

    f32x4 acc[4][4] = {};

    for (int k0 = 0; k0 < K; k0 += 64) {
        #pragma unroll
        for (int c4 = 0; c4 < 4; c4++) {
            const int c = c4 * 4 + wv;
            const int s = c * 64 + ln;
            const int rt = s >> 3;
            const int ce = ((s & 7) ^ (rt & 7)) * 8;   // T2 swizzle (both sides)
            async16(&ldsA[c * 512], A + (size_t)(bm + rt) * K + k0 + ce);
            async16(&ldsB[c * 512], B + (size_t)(bn + rt) * K + k0 + ce);
        }
        __syncthreads();
        const int mr = (wv >> 1) * 64, nc = (wv & 1) * 64;
        #pragma unroll
        for (int kk = 0; kk < 2; kk++) {
            bf16x8 af[4], bfr[4];
            #pragma unroll
            for (int m = 0; m < 4; m++) {
                const int r = mr + m * 16 + r15;
                const int off = r * 128 + ((kk * 64 + r4 * 16) ^ ((r & 7) << 4));
                af[m] = *(const bf16x8*)((const char*)ldsA + off);
            }
            #pragma unroll
            for (int n = 0; n < 4; n++) {
                const int r = nc + n * 16 + r15;
                const int off = r * 128 + ((kk * 64 + r4 * 16) ^ ((r & 7) << 4));
                bfr[n] = *(const bf16x8*)((const char*)ldsB + off);
            }
            #pragma unroll
            for (int m = 0; m < 4; m++)
                #pragma unroll
                for (int n = 0; n < 4; n++)
                    acc[m][n] = __builtin_amdgcn_mfma_f32_16x16x32_bf16(
                        af[m], bfr[n], acc[m][n], 0, 0, 0);
        }
        __syncthreads();
    }
    const int mro = bm + (wv >> 1) * 64, nco = bn + (wv & 1) * 64;
    #pragma unroll
    for (int m = 0; m < 4; m++) {
        #pragma unroll
        for (int n = 0; n < 4; n++) {
            const int col = nco + n * 16 + r15;
            const float bs = bias ? bias[col] : 0.f;
            if (mode == 2) {
                const int cout = (col >> 8) * 256 + (col & 63) * 4 + ((col >> 6) & 3);
                #pragma unroll
                for (int r = 0; r < 4; r++) {
                    const int row = mro + m * 16 + r4 * 4 + r;
                    ((ushort*)C)[(size_t)row * ldc + cout] = f2bf(acc[m][n][r] + bs);
                }
            } else if (col < Nstore) {
                #pragma unroll
                for (int r = 0; r < 4; r++) {
                    const int row = mro + m * 16 + r4 * 4 + r;
                    ((float*)C)[(size_t)row * ldc + col] = acc[m][n][r] + bs;
                }
            }
        }
    }
}

// dual-segment GEMM: blockIdx.y < My0 -> segment 0, else segment 1
__global__ __launch_bounds__(256) void gemm_dual_kernel(
    const ushort* A0, const ushort* B0, const float* b0, void* C0, int My0,
    const ushort* A1, const ushort* B1, const float* b1, void* C1,
    int K, int ldc, int Nstore, int mode)
{
    __shared__ __align__(16) ushort smem[16384];
    int by = blockIdx.y;
    if (by < My0)
        gemm_core(A0, B0, b0, C0, K, ldc, Nstore, mode, by * 128, blockIdx.x * 128, smem);
    else
        gemm_core(A1, B1, b1, C1, K, ldc, Nstore, mode, (by - My0) * 128, blockIdx.x * 128, smem);
}

// pair GEMM: bx<2 -> attx (N=132 fp32), bx==2 -> npart (N=128 fp32); shared A
__global__ __launch_bounds__(256) void gemm_pair_kernel(
    const ushort* __restrict__ A,
    const ushort* __restrict__ B0, const float* __restrict__ b0, float* __restrict__ C0,
    const ushort* __restrict__ B1, float* __restrict__ C1, int K)
{
    __shared__ __align__(16) ushort smem[16384];
    if (blockIdx.x < 2)
        gemm_core(A, B0, b0, C0, K, 132, 132, 1, blockIdx.y * 128, blockIdx.x * 128, smem);
    else
        gemm_core(A, B1, nullptr, C1, K, 128, 128, 1, blockIdx.y * 128, 0, smem);
}

// =============== LSTM scan int8 DUAL-DIRECTION core: one wave per chain ===============
// R8's dual-dir idea retried with its failure mode removed: weights live in LDS
// (2x16KB staged once, conflict-free ds_read_b128 each step), not 256 VGPRs.
// Two independent recurrence chains (fwd/bwd of the SAME chain, same L) interleave
// in one wave: dots/gates/DPP on VALU, weight re-reads on DS, proj prefetch on
// VMEM - each chain's serial latency hides under the other's issue.
// proj bf16 [ch][T][dir*256 + u*4 + g]; OBF=1: bf16 out (os elems), else fp32.
template<int OBF>
__device__ __forceinline__ void scan_dual_core(
    const ushort* __restrict__ proj,
    const uint* __restrict__ frag_f, const uint* __restrict__ frag_b,
    const float* __restrict__ ksc_f, const float* __restrict__ ksc_b,
    const int* __restrict__ lengths, void* __restrict__ out,
    int T, int os, int ch, uint* wldsf, uint* wldsb)
{
    const int l = threadIdx.x;
    const int L = lengths[ch];
    const ushort* projc = proj + (size_t)ch * T * 512;
    const float4 ksf = *(const float4*)(ksc_f + l * 4);
    const float4 ksb = *(const float4*)(ksc_b + l * 4);

    // stage both 16KB weight sets into LDS (chunk-major, lane-consecutive 16B)
    #pragma unroll
    for (int c = 0; c < 16; c++) {
        async16(&wldsf[c * 256], frag_f + c * 256 + l * 4);
        async16(&wldsb[c * 256], frag_b + c * 256 + l * 4);
    }
    asm volatile("s_waitcnt vmcnt(0)" ::: "memory");

    int hsf[16], hsb[16];
    #pragma unroll
    for (int i = 0; i < 16; i++) { hsf[i] = 0; hsb[i] = 0; }

    float cf = 0.f, cb = 0.f;
    const size_t obase = (size_t)ch * T * os;
    float*  off_ = (float*)out + obase + l;
    float*  obf_ = (float*)out + obase + (size_t)(L - 1) * os + 64 + l;
    ushort* ofh_ = (ushort*)out + obase + l;
    ushort* obh_ = (ushort*)out + obase + (size_t)(L - 1) * os + 64 + l;

    auto ldf = [&](int s) -> uint2 {
        int t = (s < L) ? s : (L - 1);
        return *(const uint2*)(projc + (size_t)t * 512 + 4 * l);
    };
    auto ldb = [&](int s) -> uint2 {
        int t = (s < L) ? (L - 1 - s) : 0;
        return *(const uint2*)(projc + (size_t)t * 512 + 256 + 4 * l);
    };
    uint2 Pf0 = ldf(0), Pf1 = ldf(1), Pf2 = ldf(2);
    uint2 Pb0 = ldb(0), Pb1 = ldb(1), Pb2 = ldb(2);

    for (int s = 0; s < L; s++) {
        int fi0 = 0, fi1 = 0, ff0 = 0, ff1 = 0, fg0 = 0, fg1 = 0, fo0 = 0, fo1 = 0;
        int bi0 = 0, bi1 = 0, bf0 = 0, bf1 = 0, bg0 = 0, bg1 = 0, bo0 = 0, bo1 = 0;
        #pragma unroll
        for (int c = 0; c < 4; c++) {
            uint4 wi = *(const uint4*)&wldsf[(0  + c) * 256 + l * 4];
            uint4 wf = *(const uint4*)&wldsf[(4  + c) * 256 + l * 4];
            uint4 wg = *(const uint4*)&wldsf[(8  + c) * 256 + l * 4];
            uint4 wo = *(const uint4*)&wldsf[(12 + c) * 256 + l * 4];
            const int h0 = hsf[c * 4 + 0], h1 = hsf[c * 4 + 1];
            const int h2 = hsf[c * 4 + 2], h3 = hsf[c * 4 + 3];
            fi0 = SDOT4(wi.x, h0, fi0); fi1 = SDOT4(wi.y, h1, fi1);
            fi0 = SDOT4(wi.z, h2, fi0); fi1 = SDOT4(wi.w, h3, fi1);
            ff0 = SDOT4(wf.x, h0, ff0); ff1 = SDOT4(wf.y, h1, ff1);
            ff0 = SDOT4(wf.z, h2, ff0); ff1 = SDOT4(wf.w, h3, ff1);
            fg0 = SDOT4(wg.x, h0, fg0); fg1 = SDOT4(wg.y, h1, fg1);
            fg0 = SDOT4(wg.z, h2, fg0); fg1 = SDOT4(wg.w, h3, fg1);
            fo0 = SDOT4(wo.x, h0, fo0); fo1 = SDOT4(wo.y, h1, fo1);
            fo0 = SDOT4(wo.z, h2, fo0); fo1 = SDOT4(wo.w, h3, fo1);
        }
        #pragma unroll
        for (int c = 0; c < 4; c++) {
            uint4 wi = *(const uint4*)&wldsb[(0  + c) * 256 + l * 4];
            uint4 wf = *(const uint4*)&wldsb[(4  + c) * 256 + l * 4];
            uint4 wg = *(const uint4*)&wldsb[(8  + c) * 256 + l * 4];
            uint4 wo = *(const uint4*)&wldsb[(12 + c) * 256 + l * 4];
            const int h0 = hsb[c * 4 + 0], h1 = hsb[c * 4 + 1];
            const int h2 = hsb[c * 4 + 2], h3 = hsb[c * 4 + 3];
            bi0 = SDOT4(wi.x, h0, bi0); bi1 = SDOT4(wi.y, h1, bi1);
            bi0 = SDOT4(wi.z, h2, bi0); bi1 = SDOT4(wi.w, h3, bi1);
            bf0 = SDOT4(wf.x, h0, bf0); bf1 = SDOT4(wf.y, h1, bf1);
            bf0 = SDOT4(wf.z, h2, bf0); bf1 = SDOT4(wf.w, h3, bf1);
            bg0 = SDOT4(wg.x, h0, bg0); bg1 = SDOT4(wg.y, h1, bg1);
            bg0 = SDOT4(wg.z, h2, bg0); bg1 = SDOT4(wg.w, h3, bg1);
            bo0 = SDOT4(wo.x, h0, bo0); bo1 = SDOT4(wo.y, h1, bo1);
            bo0 = SDOT4(wo.z, h2, bo0); bo1 = SDOT4(wo.w, h3, bo1);
        }
        // fwd gates
        const float ivf = fast_sig(fmaf((float)(fi0 + fi1), ksf.x, __uint_as_float(Pf0.x << 16)));
        const float fvf = fast_sig(fmaf((float)(ff0 + ff1), ksf.y, __uint_as_float(Pf0.x & 0xffff0000u)));
        const float gvf = fast_tanh(fmaf((float)(fg0 + fg1), ksf.z, __uint_as_float(Pf0.y << 16)));
        const float ovf = fast_sig(fmaf((float)(fo0 + fo1), ksf.w, __uint_as_float(Pf0.y & 0xffff0000u)));
        // bwd gates
        const float ivb = fast_sig(fmaf((float)(bi0 + bi1), ksb.x, __uint_as_float(Pb0.x << 16)));
        const float fvb = fast_sig(fmaf((float)(bf0 + bf1), ksb.y, __uint_as_float(Pb0.x & 0xffff0000u)));
        const float gvb = fast_tanh(fmaf((float)(bg0 + bg1), ksb.z, __uint_as_float(Pb0.y << 16)));
        const float ovb = fast_sig(fmaf((float)(bo0 + bo1), ksb.w, __uint_as_float(Pb0.y & 0xffff0000u)));

        cf = fmaf(fvf, cf, ivf * gvf);
        cb = fmaf(fvb, cb, ivb * gvb);
        const float hvf = ovf * fast_tanh(cf);
        const float hvb = ovb * fast_tanh(cb);

        if (OBF) {
            *ofh_ = f2bf(hvf); ofh_ += os;
            *obh_ = f2bf(hvb); obh_ -= os;
        } else {
            *off_ = hvf; off_ += os;
            *obf_ = hvb; obf_ -= os;
        }

        // redistribute both h's: int8 quant, DPP quad-pack, 16 readlanes each
        int qf = __float2int_rn(hvf * 127.f) & 0xff;
        int qb = __float2int_rn(hvb * 127.f) & 0xff;
        int tf1 = dpp_xor1(qf);
        int tb1 = dpp_xor1(qb);
        int vf01 = (l & 1) ? (tf1 | (qf << 8)) : (qf | (tf1 << 8));
        int vb01 = (l & 1) ? (tb1 | (qb << 8)) : (qb | (tb1 << 8));
        int tf2 = dpp_xor2(vf01);
        int tb2 = dpp_xor2(vb01);
        int vf = (l & 2) ? ((tf2 & 0xffff) | (vf01 << 16)) : ((vf01 & 0xffff) | (tf2 << 16));
        int vb = (l & 2) ? ((tb2 & 0xffff) | (vb01 << 16)) : ((vb01 & 0xffff) | (tb2 << 16));
        #pragma unroll
        for (int i = 0; i < 16; i++) {
            hsf[i] = __builtin_amdgcn_readlane(vf, 4 * i);
            hsb[i] = __builtin_amdgcn_readlane(vb, 4 * i);
        }

        Pf0 = Pf1; Pf1 = Pf2; Pf2 = ldf(s + 3);
        Pb0 = Pb1; Pb1 = Pb2; Pb2 = ldb(s + 3);
    }

    // zero-fill masked region t in [L, T), cols 0..127 (both dirs)
    for (int idx = l; idx < (T - L) * 128; idx += 64) {
        int t = L + (idx >> 7);
        int c = idx & 127;
        if (OBF) ((ushort*)out)[obase + (size_t)t * os + c] = 0;
        else     ((float*)out)[obase + (size_t)t * os + c] = 0.f;
    }
}

// fused dual-segment scans: bx < nA -> segment A (question), else B (header).
template<int OBFA, int OBFB>
__global__ __launch_bounds__(64, 1) void scan_fused_kernel(
    int nA,
    const ushort* projA, const uint* fAf, const uint* fAb,
    const float* kAf, const float* kAb, const int* lenA, void* outA, int TA, int osA,
    const ushort* projB, const uint* fBf, const uint* fBb,
    const float* kBf, const float* kBb, const int* lenB, void* outB, int TB, int osB)
{
    __shared__ __align__(16) uint wlds[8192];   // 32 KB: fwd + bwd weights
    const int bx = blockIdx.x;
    if (bx < nA)
        scan_dual_core<OBFA>(projA, fAf, fAb, kAf, kAb, lenA, outA, TA, osA,
                             bx, wlds, wlds + 4096);
    else
        scan_dual_core<OBFB>(projB, fBf, fBb, kBf, kBb, lenB, outB, TB, osB,
                             bx - nA, wlds, wlds + 4096);
}

// ---------------- one-hot + zero pad into A_pad cols 128..191 (bf16) ----------------
__global__ __launch_bounds__(256) void onehot_pad_kernel(
    const int* __restrict__ knowledge, ushort* __restrict__ A_pad)
{
    int row = blockIdx.x * 256 + threadIdx.x;
    if (row >= 96 * 512) return;
    int kn = knowledge[row];
    uint words[8] = {0, 0, 0, 0, 0, 0, 0, 0};
    words[kn >> 1] = (kn & 1) ? 0x3F800000u : 0x00003F80u;   // bf16 1.0
    uint4* dst = (uint4*)(A_pad + (size_t)row * 192 + 128);
    dst[0] = make_uint4(words[0], words[1], words[2], words[3]);
    dst[1] = make_uint4(words[4], words[5], words[6], words[7]);
    uint4 z = make_uint4(0, 0, 0, 0);
    dst[2] = z; dst[3] = z; dst[4] = z; dst[5] = z; dst[6] = z; dst[7] = z;
}

// ---------------- header select + gather: wenc_hs in smem -> hs_ob ----------------
__global__ __launch_bounds__(256) void hs_merge_kernel(
    const float* __restrict__ h1_head, const int* __restrict__ l_hpu,
    const int* __restrict__ knowledge_header,
    const int* __restrict__ wc, const int* __restrict__ wn,
    float* __restrict__ hs_ob)
{
    int b = blockIdx.x, tid = threadIdx.x;
    __shared__ float whs[16][132];
    for (int idx = tid; idx < 16 * 132; idx += 256) {
        int u = idx / 132, c = idx - u * 132;
        int g = b * 16 + u;
        int L = l_hpu[g];
        float v;
        if (c < 128) v = h1_head[((size_t)g * 8 + (L - 1)) * 128 + c];
        else v = ((c - 128) == knowledge_header[g]) ? 1.f : 0.f;
        whs[u][c] = v;
    }
    __syncthreads();
    for (int idx = tid; idx < 4 * 132; idx += 256) {
        int w = idx / 132, c = idx - w * 132;
        int col = (w < wn[b]) ? wc[b * 4 + w] : 0;
        hs_ob[((size_t)b * 4 + w) * 132 + c] = whs[col][c];
    }
}

// ------- fused attention: scores(attx) -> softmax -> context(A_pad) -> vec -------
__global__ __launch_bounds__(256) void att_vec_kernel(
    const float* __restrict__ attx, const float* __restrict__ hs_ob,
    const ushort* __restrict__ A_pad, const int* __restrict__ l_n,
    const float* __restrict__ Wc_w, const float* __restrict__ Wc_b,
    const float* __restrict__ Whs_w, const float* __restrict__ Whs_b,
    const float* __restrict__ Wop_w, const float* __restrict__ Wop_b,
    const int* __restrict__ wn, const int* __restrict__ wo,
    float* __restrict__ vec)
{
    int b = blockIdx.x, w = blockIdx.y;
    int tid = threadIdx.x;
    int L = l_n[b];
    __shared__ float q[132];
    __shared__ float sc[512];
    __shared__ float red[256];
    __shared__ float cn[140];
    if (tid < 132) q[tid] = hs_ob[((size_t)b * 4 + w) * 132 + tid];
    __syncthreads();
    for (int t = tid; t < 512; t += 256) {
        float s = -1e30f;
        if (t < L) {
            const float* ax = attx + ((size_t)b * 512 + t) * 132;
            float s0 = 0.f, s1 = 0.f, s2 = 0.f, s3 = 0.f;
            #pragma unroll
            for (int d = 0; d < 132; d += 4) {
                s0 = fmaf(ax[d + 0], q[d + 0], s0);
                s1 = fmaf(ax[d + 1], q[d + 1], s1);
                s2 = fmaf(ax[d + 2], q[d + 2], s2);
                s3 = fmaf(ax[d + 3], q[d + 3], s3);
            }
            s = (s0 + s1) + (s2 + s3);
        }
        sc[t] = s;
    }
    __syncthreads();
    red[tid] = fmaxf(sc[tid], sc[tid + 256]);
    __syncthreads();
    for (int off = 128; off > 0; off >>= 1) {
        if (tid < off) red[tid] = fmaxf(red[tid], red[tid + off]);
        __syncthreads();
    }
    float m = red[0];
    __syncthreads();
    float ps = 0.f;
    for (int t = tid; t < 512; t += 256) {
        float e = (t < L) ? __expf(sc[t] - m) : 0.f;
        sc[t] = e;
        ps += e;
    }
    red[tid] = ps;
    __syncthreads();
    for (int off = 128; off > 0; off >>= 1) {
        if (tid < off) red[tid] += red[tid + off];
        __syncthreads();
    }
    float inv = 1.f / red[0];
    if (tid < 140) {
        float acc = 0.f;
        const ushort* col = A_pad + (size_t)b * 512 * 192 + tid;
        for (int t = 0; t < L; t++)
            acc = fmaf(sc[t], __uint_as_float((uint)col[(size_t)t * 192] << 16), acc);
        cn[tid] = acc * inv;
    }
    __syncthreads();
    float* vrow = vec + ((size_t)b * 4 + w) * 384;
    if (tid < 128) {
        float acc = Wc_b[tid];
        const float* r = Wc_w + (size_t)tid * 140;
        for (int d = 0; d < 140; d++) acc = fmaf(r[d], cn[d], acc);
        vrow[tid] = acc;
    } else {
        int jj = tid - 128;
        float acc = Whs_b[jj];
        const float* r = Whs_w + (size_t)jj * 132;
        for (int d = 0; d < 132; d++) acc = fmaf(r[d], q[d], acc);
        vrow[128 + jj] = acc;
    }
    if (tid < 128) {
        int op = (w < wn[b]) ? wo[b * 4 + w] : 0;
        vrow[256 + tid] = Wop_b[tid] + Wop_w[tid * 4 + op];
    }
}

// ---------------- SIMT GEMM (vpart): C = A @ B^T (+bias) ----------------
__global__ __launch_bounds__(256) void gemm_bias_kernel(
    const float* __restrict__ A, const float* __restrict__ B,
    const float* __restrict__ bias, float* __restrict__ C,
    int M, int N, int K, int lda, int ldb, int ldc)
{
    __shared__ float As[16][68];
    __shared__ float Bs[16][68];
    const int tid = threadIdx.x;
    const int bm = blockIdx.y * 64;
    const int bn = blockIdx.x * 64;
    const int tx = tid & 15;
    const int ty = tid >> 4;
    const int lm = tid & 63;
    const int lk = (tid >> 6) << 2;
    float acc[4][4] = {};
    const int arow = bm + lm;
    const int brow = bn + lm;

    for (int k0 = 0; k0 < K; k0 += 16) {
        int k = k0 + lk;
        float4 av = make_float4(0.f, 0.f, 0.f, 0.f);
        float4 bv = make_float4(0.f, 0.f, 0.f, 0.f);
        if (arow < M) {
            if (k + 4 <= K) av = *(const float4*)(A + (size_t)arow * lda + k);
            else { float* p = (float*)&av;
                for (int i = 0; i < 4; i++) if (k + i < K) p[i] = A[(size_t)arow * lda + k + i]; }
        }
        if (brow < N) {
            if (k + 4 <= K) bv = *(const float4*)(B + (size_t)brow * ldb + k);
            else { float* p = (float*)&bv;
                for (int i = 0; i < 4; i++) if (k + i < K) p[i] = B[(size_t)brow * ldb + k + i]; }
        }
        As[lk + 0][lm] = av.x; As[lk + 1][lm] = av.y; As[lk + 2][lm] = av.z; As[lk + 3][lm] = av.w;
        Bs[lk + 0][lm] = bv.x; Bs[lk + 1][lm] = bv.y; Bs[lk + 2][lm] = bv.z; Bs[lk + 3][lm] = bv.w;
        __syncthreads();
        #pragma unroll
        for (int kk = 0; kk < 16; kk++) {
            float a[4], bb[4];
            #pragma unroll
            for (int i = 0; i < 4; i++) a[i] = As[kk][ty * 4 + i];
            #pragma unroll
            for (int j = 0; j < 4; j++) bb[j] = Bs[kk][tx * 4 + j];
            #pragma unroll
            for (int i = 0; i < 4; i++)
                #pragma unroll
                for (int j = 0; j < 4; j++)
                    acc[i][j] = fmaf(a[i], bb[j], acc[i][j]);
        }
        __syncthreads();
    }
    #pragma unroll
    for (int i = 0; i < 4; i++) {
        int row = bm + ty * 4 + i;
        if (row >= M) continue;
        #pragma unroll
        for (int j = 0; j < 4; j++) {
            int col = bn + tx * 4 + j;
            if (col < N) C[(size_t)row * ldc + col] = acc[i][j] + (bias ? bias[col] : 0.f);
        }
    }
}

// ---------------- final: out[b,w,t,:] = tanh(vpart+npart)@out2.T + b, masked ----------------
__global__ __launch_bounds__(256) void final_kernel(
    const float* __restrict__ vpart, const float* __restrict__ npart,
    const float* __restrict__ out2_w, const float* __restrict__ out2_b,
    const int* __restrict__ l_n, float* __restrict__ out)
{
    int b = blockIdx.y;
    int tid = threadIdx.x;
    int t = blockIdx.x * 256 + tid;
    __shared__ float vp[512];
    __shared__ float w2[256];
    w2[tid] = out2_w[tid];
    for (int i = tid; i < 512; i += 256) vp[i] = vpart[(size_t)b * 512 + i];
    __syncthreads();
    int L = l_n[b];
    float s[4][2];
    if (t < L) {
        float b0 = out2_b[0], b1 = out2_b[1];
        #pragma unroll
        for (int w = 0; w < 4; w++) { s[w][0] = b0; s[w][1] = b1; }
        const float4* np4 = (const float4*)(npart + ((size_t)b * 512 + t) * 128);
        for (int h4 = 0; h4 < 32; h4++) {
            float4 n = np4[h4];
            const float* nf = (const float*)&n;
            #pragma unroll
            for (int e = 0; e < 4; e++) {
                int h = h4 * 4 + e;
                float nv = nf[e];
                float w0 = w2[h], w1 = w2[128 + h];
                #pragma unroll
                for (int w = 0; w < 4; w++) {
                    float z = fast_tanh(vp[w * 128 + h] + nv);
                    s[w][0] = fmaf(z, w0, s[w][0]);
                    s[w][1] = fmaf(z, w1, s[w][1]);
                }
            }
        }
    } else {
        #pragma unroll
        for (int w = 0; w < 4; w++) { s[w][0] = NEGV; s[w][1] = NEGV; }
    }
    #pragma unroll
    for (int w = 0; w < 4; w++) {
        size_t o = (((size_t)b * 4 + w) * 512 + t) * 2;
        out[o + 0] = s[w][0];
        out[o + 1] = s[w][1];
    }
}

// ---------------------------------------------------------------------------
extern "C" void kernel_launch(void* const* d_in, const int* in_sizes, int n_in,
                              void* d_out, int out_size, void* d_ws, size_t ws_size,
                              hipStream_t stream)
{
    const float* wemb_n   = (const float*)d_in[0];
    const float* wemb_hpu = (const float*)d_in[1];
    const float* Wih_n0f = (const float*)d_in[2];
    const float* Whh_n0f = (const float*)d_in[3];
    const float* b_n0f   = (const float*)d_in[4];
    const float* Wih_n0b = (const float*)d_in[5];
    const float* Whh_n0b = (const float*)d_in[6];
    const float* b_n0b   = (const float*)d_in[7];
    const float* Wih_n1f = (const float*)d_in[8];
    const float* Whh_n1f = (const float*)d_in[9];
    const float* b_n1f   = (const float*)d_in[10];
    const float* Wih_n1b = (const float*)d_in[11];
    const float* Whh_n1b = (const float*)d_in[12];
    const float* b_n1b   = (const float*)d_in[13];
    const float* Wih_h0f = (const float*)d_in[14];
    const float* Whh_h0f = (const float*)d_in[15];
    const float* b_h0f   = (const float*)d_in[16];
    const float* Wih_h0b = (const float*)d_in[17];
    const float* Whh_h0b = (const float*)d_in[18];
    const float* b_h0b   = (const float*)d_in[19];
    const float* Wih_h1f = (const float*)d_in[20];
    const float* Whh_h1f = (const float*)d_in[21];
    const float* b_h1f   = (const float*)d_in[22];
    const float* Wih_h1b = (const float*)d_in[23];
    const float* Whh_h1b = (const float*)d_in[24];
    const float* b_h1b   = (const float*)d_in[25];
    const float* Watt_w  = (const float*)d_in[26];
    const float* Watt_b  = (const float*)d_in[27];
    const float* Wc_w    = (const float*)d_in[28];
    const float* Wc_b    = (const float*)d_in[29];
    const float* Whs_w   = (const float*)d_in[30];
    const float* Whs_b   = (const float*)d_in[31];
    const float* Wop_w   = (const float*)d_in[32];
    const float* Wop_b   = (const float*)d_in[33];
    const float* out1_w  = (const float*)d_in[34];
    const float* out1_b  = (const float*)d_in[35];
    const float* out2_w  = (const float*)d_in[36];
    const float* out2_b  = (const float*)d_in[37];
    const int* l_n   = (const int*)d_in[38];
    const int* l_hpu = (const int*)d_in[39];
    const int* wc    = (const int*)d_in[40];
    const int* wn    = (const int*)d_in[41];
    const int* wo    = (const int*)d_in[42];
    const int* knowledge        = (const int*)d_in[43];
    const int* knowledge_header = (const int*)d_in[44];

    float* ws = (float*)d_ws;
    // ---- workspace map (float offsets; lifetimes annotated) ----
    ushort* proj_q  = (ushort*)(ws + 0);          // [0,12582912)  49152x512 bf16
    ushort* proj_h  = (ushort*)(ws + 12582912);   // [12582912,15728640) 12288x512 bf16
    ushort* AbfH0   = (ushort*)(ws + 15728640);   // wemb_hpu bf16 (dead after G0)
    ushort* A_pad   = (ushort*)(ws + 15728640);   // [49152][192] bf16 (written post-G0)
    ushort* Bp_att  = (ushort*)(ws + 20447232);   // 256x192
    ushort* Bp_out  = (ushort*)(ws + 20471808);   // 128x192
    float*  bias_pad = ws + 20484096;             // 256
    ushort* h_h0_bf = (ushort*)(ws + 22057216);   // 12288x128 bf16
    ushort* WbfQ0   = (ushort*)(ws + 22843648);   // 512x512 bf16
    ushort* WbfH0   = (ushort*)(ws + 22974720);
    ushort* WbfQ1   = (ushort*)(ws + 23105792);   // 512x128
    ushort* WbfH1   = (ushort*)(ws + 23138560);
    uint*   frag8   = (uint*)(ws + 23171328);     // 8 x 4096 dwords int8 Whh (LDS-tiled)
    float*  ksc     = ws + 23204096;              // 8 x 256 scales
    float*  bias_all = ws + 23236864;             // [4][512]
    ushort* AbfQ0   = (ushort*)(ws + 25165824);   // wemb_n bf16 (dead after G0)
    float*  h1_head = ws + 26738688;              // 12288x128 fp32 (post-G0)
    ushort* wenc0_bf = (ushort*)(ws + 31457280);  // 49152x128 bf16 (post-G0)
    float*  attx    = ws + 0;                     // reuse proj_q after QS1
    float*  npart   = ws + 6488064;               // [6488064,12779520)
    float*  hs_ob   = ws + 38541312;
    float*  vec     = ws + 38645760;
    float*  vpart   = ws + 38793216;
    float*  outp    = (float*)d_out;

    dim3 blk(256);
    auto cast2 = [&](const float* a, const float* b, ushort* oa, ushort* ob, int na, int nb) {
        cast2_bf16_kernel<<<dim3(((na + nb) / 8 + 255) / 256), blk, 0, stream>>>(a, b, oa, ob, na, nb);
    };

    // ---- prep + casts ----
    prep_all_kernel<<<dim3(401), blk, 0, stream>>>(
        Whh_n0f, Whh_n0b, Whh_n1f, Whh_n1b, Whh_h0f, Whh_h0b, Whh_h1f, Whh_h1b,
        frag8, ksc,
        b_n0f, b_n0b, b_n1f, b_n1b, b_h0f, b_h0b, b_h1f, b_h1b, bias_all,
        Watt_w, Bp_att, out1_w, Bp_out, Watt_b, bias_pad);
    cast2(wemb_n, wemb_hpu, AbfQ0, AbfH0, 96 * 512 * 512, 1536 * 8 * 512);
    cast2(Wih_n0f, Wih_n0b, WbfQ0, WbfQ0 + 256 * 512, 256 * 512, 256 * 512);
    cast2(Wih_h0f, Wih_h0b, WbfH0, WbfH0 + 256 * 512, 256 * 512, 256 * 512);
    cast2(Wih_n1f, Wih_n1b, WbfQ1, WbfQ1 + 256 * 128, 256 * 128, 256 * 128);
    cast2(Wih_h1f, Wih_h1b, WbfH1, WbfH1 + 256 * 128, 256 * 128, 256 * 128);

    // ---- layer 0 projections (QG0 + HG0 in one dispatch) ----
    gemm_dual_kernel<<<dim3(4, 480), blk, 0, stream>>>(
        AbfQ0, WbfQ0, bias_all + 0 * 512, proj_q, 384,
        AbfH0, WbfH0, bias_all + 2 * 512, proj_h,
        512, 512, 512, 2);
    onehot_pad_kernel<<<dim3(192), blk, 0, stream>>>(knowledge, A_pad);

    // ---- layer-0 scans: QS0 || HS0 fused, dual-direction per wave ----
    scan_fused_kernel<1, 1><<<dim3(96 + 1536), dim3(64), 0, stream>>>(
        96,
        proj_q, frag8 + 0 * 4096, frag8 + 1 * 4096, ksc + 0 * 256, ksc + 1 * 256,
        l_n, wenc0_bf, 512, 128,
        proj_h, frag8 + 4 * 4096, frag8 + 5 * 4096, ksc + 4 * 256, ksc + 5 * 256,
        l_hpu, h_h0_bf, 8, 128);

    // ---- layer 1 projections (QG1 + HG1 in one dispatch) ----
    gemm_dual_kernel<<<dim3(4, 480), blk, 0, stream>>>(
        wenc0_bf, WbfQ1, bias_all + 1 * 512, proj_q, 384,
        h_h0_bf, WbfH1, bias_all + 3 * 512, proj_h,
        128, 512, 512, 2);

    // ---- layer-1 scans: QS1 (A_pad bf16, stride 192) || HS1 (fp32) fused ----
    scan_fused_kernel<1, 0><<<dim3(96 + 1536), dim3(64), 0, stream>>>(
        96,
        proj_q, frag8 + 2 * 4096, frag8 + 3 * 4096, ksc + 2 * 256, ksc + 3 * 256,
        l_n, A_pad, 512, 192,
        proj_h, frag8 + 6 * 4096, frag8 + 7 * 4096, ksc + 6 * 256, ksc + 7 * 256,
        l_hpu, h1_head, 8, 128);

    // ---- tail ----
    hs_merge_kernel<<<dim3(96), blk, 0, stream>>>(h1_head, l_hpu, knowledge_header,
                                                  wc, wn, hs_ob);
    gemm_pair_kernel<<<dim3(3, 384), blk, 0, stream>>>(
        A_pad, Bp_att, bias_pad, attx, Bp_out, npart, 192);
    att_vec_kernel<<<dim3(96, 4), blk, 0, stream>>>(attx, hs_ob, A_pad, l_n,
                                                    Wc_w, Wc_b, Whs_w, Whs_b,
                                                    Wop_w, Wop_b, wn, wo, vec);
    gemm_bias_kernel<<<dim3(2, 6), blk, 0, stream>>>(vec, out1_w, out1_b, vpart,
                                                     384, 128, 384, 384, 524, 128);
    final_kernel<<<dim3(2, 96), blk, 0, stream>>>(vpart, npart, out2_w, out2_b, l_n, outp);
}

// Round 18
// 656.313 us; speedup vs baseline: 1.4654x; 1.4654x over previous
//
#include <hip/hip_runtime.h>
#include <math.h>

#define NEGV -1e10f

typedef __bf16 bf16x8 __attribute__((ext_vector_type(8)));
typedef float f32x4 __attribute__((ext_vector_type(4)));
typedef unsigned short ushort;
typedef unsigned int uint;

__device__ __forceinline__ float fast_tanh(float x) {
    float e = __expf(2.0f * x);
    return fmaf(-2.f, __builtin_amdgcn_rcpf(e + 1.f), 1.f);
}
__device__ __forceinline__ float fast_sig(float x) {
    return __builtin_amdgcn_rcpf(1.f + __expf(-x));
}
__device__ __forceinline__ ushort f2bf(float x) {
    unsigned int b = __float_as_uint(x);
    b += 0x7fffu + ((b >> 16) & 1u);   // RNE
    return (ushort)(b >> 16);
}
#if __has_builtin(__builtin_amdgcn_sdot4)
#define SDOT4(a, b, c) __builtin_amdgcn_sdot4((int)(a), (int)(b), (int)(c), false)
#else
__device__ __forceinline__ int SDOT4(int a, int b, int c) {
    #pragma unroll
    for (int k = 0; k < 4; k++) {
        int xa = (a >> (8 * k)) & 0xff; xa = (xa ^ 0x80) - 0x80;
        int xb = (b >> (8 * k)) & 0xff; xb = (xb ^ 0x80) - 0x80;
        c += xa * xb;
    }
    return c;
}
#endif
// VALU-pipe lane swaps within quads: quad_perm[1,0,3,2]=0xB1 (lane^1),
// quad_perm[2,3,0,1]=0x4E (lane^2)
__device__ __forceinline__ int dpp_xor1(int v) {
    return __builtin_amdgcn_update_dpp(0, v, 0xB1, 0xf, 0xf, true);
}
__device__ __forceinline__ int dpp_xor2(int v) {
    return __builtin_amdgcn_update_dpp(0, v, 0x4E, 0xf, 0xf, true);
}
// async 16B global -> LDS (dest = wave-uniform base + lane*16, src per-lane)
__device__ __forceinline__ void async16(void* l, const void* g) {
    __builtin_amdgcn_global_load_lds(
        (const __attribute__((address_space(1))) void*)g,
        (__attribute__((address_space(3))) void*)l,
        16, 0, 0);
}

// ---------------- dual fp32 -> bf16 cast (both n % 8 == 0) ----------------
__global__ __launch_bounds__(256) void cast2_bf16_kernel(
    const float* __restrict__ inA, const float* __restrict__ inB,
    ushort* __restrict__ outA, ushort* __restrict__ outB, int nA, int nB)
{
    int i = (blockIdx.x * 256 + threadIdx.x) * 8;
    const float* in;
    ushort* out;
    if (i < nA) { in = inA; out = outA; }
    else {
        i -= nA;
        if (i >= nB) return;
        in = inB; out = outB;
    }
    float4 a = *(const float4*)(in + i);
    float4 b = *(const float4*)(in + i + 4);
    uint4 o;
    o.x = (unsigned)f2bf(a.x) | ((unsigned)f2bf(a.y) << 16);
    o.y = (unsigned)f2bf(a.z) | ((unsigned)f2bf(a.w) << 16);
    o.z = (unsigned)f2bf(b.x) | ((unsigned)f2bf(b.y) << 16);
    o.w = (unsigned)f2bf(b.z) | ((unsigned)f2bf(b.w) << 16);
    *(uint4*)(out + i) = o;
}

// ============ prep_all: whh-int8 pack | bias concat | Bp_att | Bp_out | bias_pad ============
// blocks [0,8): per-mat int8 pack, LDS-staging layout (chunk-major, lane-consecutive):
//   dword j = g*16+jj of lane l -> frag8[mat*4096 + (j>>2)*256 + l*4 + (j&3)]
//   ksc[mat*256 + l*4 + g] = (amax/127)/127
// blocks [8,16): bias_all; [16,272): Bp_att rows; [272,400): Bp_out rows; 400: bias_pad
__global__ __launch_bounds__(256) void prep_all_kernel(
    const float* W0, const float* W1, const float* W2, const float* W3,
    const float* W4, const float* W5, const float* W6, const float* W7,
    uint* __restrict__ frag8, float* __restrict__ ksc,
    const float* s0, const float* s1, const float* s2, const float* s3,
    const float* s4, const float* s5, const float* s6, const float* s7,
    float* __restrict__ bias_all,
    const float* __restrict__ Watt_w, ushort* __restrict__ Bp_att,
    const float* __restrict__ out1_w, ushort* __restrict__ Bp_out,
    const float* __restrict__ Watt_b, float* __restrict__ bias_pad)
{
    const int bx = blockIdx.x, tid = threadIdx.x;
    if (bx < 8) {
        const float* Ws[8] = {W0, W1, W2, W3, W4, W5, W6, W7};
        const float* W = Ws[bx];
        int l = tid >> 2, g = tid & 3;
        const float* row = W + (size_t)(g * 64 + l) * 64;
        float amax = 0.f;
        for (int k = 0; k < 64; k++) amax = fmaxf(amax, fabsf(row[k]));
        float sw = fmaxf(amax, 1e-12f) / 127.f;
        float inv = 127.f / fmaxf(amax, 1e-12f);
        ksc[bx * 256 + l * 4 + g] = sw / 127.f;
        for (int jj = 0; jj < 16; jj++) {
            uint wd = 0;
            #pragma unroll
            for (int k = 0; k < 4; k++) {
                int q = __float2int_rn(row[4 * jj + k] * inv);
                q = max(-127, min(127, q));
                wd |= ((uint)(q & 0xff)) << (8 * k);
            }
            int j = g * 16 + jj;
            frag8[bx * 4096 + (j >> 2) * 256 + l * 4 + (j & 3)] = wd;
        }
    } else if (bx < 16) {
        const float* srcs[8] = {s0, s1, s2, s3, s4, s5, s6, s7};
        bias_all[(bx - 8) * 256 + tid] = srcs[bx - 8][tid];
    } else if (bx < 272) {
        int rowi = bx - 16;
        if (tid < 96) {
            float a = 0.f, b = 0.f;
            if (rowi < 132) {
                const float* s = Watt_w + (size_t)rowi * 140;
                if (2 * tid < 140) a = s[2 * tid];
                if (2 * tid + 1 < 140) b = s[2 * tid + 1];
            }
            ((uint*)(Bp_att + (size_t)rowi * 192))[tid] =
                (uint)f2bf(a) | ((uint)f2bf(b) << 16);
        }
    } else if (bx < 400) {
        int rowi = bx - 272;
        if (tid < 96) {
            const float* s = out1_w + (size_t)rowi * 524 + 384;
            float a = (2 * tid < 140) ? s[2 * tid] : 0.f;
            float b = (2 * tid + 1 < 140) ? s[2 * tid + 1] : 0.f;
            ((uint*)(Bp_out + (size_t)rowi * 192))[tid] =
                (uint)f2bf(a) | ((uint)f2bf(b) << 16);
        }
    } else {
        bias_pad[tid] = (tid < 132) ? Watt_b[tid] : 0.f;
    }
}

// =============== shared MFMA GEMM core: C = A[.,K]bf16 @ B[.,K]bf16^T (+bias) ===============
// mode 1: fp32 store, cols < Nstore. mode 2: bf16 store, scan-perm layout
// (col = dir*256+g*64+u -> dir*256 + u*4 + g), ldc elements.
__device__ __forceinline__ void gemm_core(
    const ushort* __restrict__ A, const ushort* __restrict__ B,
    const float* __restrict__ bias, void* __restrict__ C,
    int K, int ldc, int Nstore, int mode, int bm, int bn, ushort* lds)
{
    ushort* ldsA = lds;
    ushort* ldsB = lds + 8192;
    const int tid = threadIdx.x;
    const int wv = tid >> 6, ln = tid & 63;
    const int r15 = ln & 15, r4 = ln >> 4;

    f32x4 acc[4][4] = {};

    for (int k0 = 0; k0 < K; k0 += 64) {
        #pragma unroll
        for (int c4 = 0; c4 < 4; c4++) {
            const int c = c4 * 4 + wv;
            const int s = c * 64 + ln;
            const int rt = s >> 3;
            const int ce = ((s & 7) ^ (rt & 7)) * 8;   // T2 swizzle (both sides)
            async16(&ldsA[c * 512], A + (size_t)(bm + rt) * K + k0 + ce);
            async16(&ldsB[c * 512], B + (size_t)(bn + rt) * K + k0 + ce);
        }
        __syncthreads();
        const int mr = (wv >> 1) * 64, nc = (wv & 1) * 64;
        #pragma unroll
        for (int kk = 0; kk < 2; kk++) {
            bf16x8 af[4], bfr[4];
            #pragma unroll
            for (int m = 0; m < 4; m++) {
                const int r = mr + m * 16 + r15;
                const int off = r * 128 + ((kk * 64 + r4 * 16) ^ ((r & 7) << 4));
                af[m] = *(const bf16x8*)((const char*)ldsA + off);
            }
            #pragma unroll
            for (int n = 0; n < 4; n++) {
                const int r = nc + n * 16 + r15;
                const int off = r * 128 + ((kk * 64 + r4 * 16) ^ ((r & 7) << 4));
                bfr[n] = *(const bf16x8*)((const char*)ldsB + off);
            }
            #pragma unroll
            for (int m = 0; m < 4; m++)
                #pragma unroll
                for (int n = 0; n < 4; n++)
                    acc[m][n] = __builtin_amdgcn_mfma_f32_16x16x32_bf16(
                        af[m], bfr[n], acc[m][n], 0, 0, 0);
        }
        __syncthreads();
    }
    const int mro = bm + (wv >> 1) * 64, nco = bn + (wv & 1) * 64;
    #pragma unroll
    for (int m = 0; m < 4; m++) {
        #pragma unroll
        for (int n = 0; n < 4; n++) {
            const int col = nco + n * 16 + r15;
            const float bs = bias ? bias[col] : 0.f;
            if (mode == 2) {
                const int cout = (col >> 8) * 256 + (col & 63) * 4 + ((col >> 6) & 3);
                #pragma unroll
                for (int r = 0; r < 4; r++) {
                    const int row = mro + m * 16 + r4 * 4 + r;
                    ((ushort*)C)[(size_t)row * ldc + cout] = f2bf(acc[m][n][r] + bs);
                }
            } else if (col < Nstore) {
                #pragma unroll
                for (int r = 0; r < 4; r++) {
                    const int row = mro + m * 16 + r4 * 4 + r;
                    ((float*)C)[(size_t)row * ldc + col] = acc[m][n][r] + bs;
                }
            }
        }
    }
}

// dual-segment GEMM: blockIdx.y < My0 -> segment 0, else segment 1
__global__ __launch_bounds__(256) void gemm_dual_kernel(
    const ushort* A0, const ushort* B0, const float* b0, void* C0, int My0,
    const ushort* A1, const ushort* B1, const float* b1, void* C1,
    int K, int ldc, int Nstore, int mode)
{
    __shared__ __align__(16) ushort smem[16384];
    int by = blockIdx.y;
    if (by < My0)
        gemm_core(A0, B0, b0, C0, K, ldc, Nstore, mode, by * 128, blockIdx.x * 128, smem);
    else
        gemm_core(A1, B1, b1, C1, K, ldc, Nstore, mode, (by - My0) * 128, blockIdx.x * 128, smem);
}

// pair GEMM: bx<2 -> attx (N=132 fp32), bx==2 -> npart (N=128 fp32); shared A
__global__ __launch_bounds__(256) void gemm_pair_kernel(
    const ushort* __restrict__ A,
    const ushort* __restrict__ B0, const float* __restrict__ b0, float* __restrict__ C0,
    const ushort* __restrict__ B1, float* __restrict__ C1, int K)
{
    __shared__ __align__(16) ushort smem[16384];
    if (blockIdx.x < 2)
        gemm_core(A, B0, b0, C0, K, 132, 132, 1, blockIdx.y * 128, blockIdx.x * 128, smem);
    else
        gemm_core(A, B1, nullptr, C1, K, 128, 128, 1, blockIdx.y * 128, 0, smem);
}

// =============== LSTM scan int8 core: one wave per (chain,dir) ===============
// R16 structure (best known): weights staged once into LDS (16KB), re-read each
// step via conflict-free ds_read_b128 on the DS pipe; h-redistribution via DPP
// quad_perm (VALU) + 16 readlanes; proj prefetch depth-3 on VMEM. Per-row int8
// quant, scale ksc[l*4+g]. R17's dual-direction variant regressed (compiler
// serializes the two chains at the lgkmcnt waits) - do not retry.
// proj bf16 [ch][T][dir*256 + u*4 + g]; OBF=1: bf16 out (os elems), else fp32.
template<int OBF>
__device__ __forceinline__ void scan_core(
    const ushort* __restrict__ proj,
    const uint* __restrict__ frag_f, const uint* __restrict__ frag_b,
    const float* __restrict__ ksc_f, const float* __restrict__ ksc_b,
    const int* __restrict__ lengths, void* __restrict__ out,
    int T, int os, int ch, int dir, uint* wlds)
{
    const int l = threadIdx.x;
    const int L = lengths[ch];
    const ushort* projc = proj + (size_t)ch * T * 512 + dir * 256;
    const uint* fragm = dir ? frag_b : frag_f;
    const float4 ks = *(const float4*)((dir ? ksc_b : ksc_f) + l * 4);

    // stage 16KB weights into LDS (chunk-major, lane-consecutive 16B)
    #pragma unroll
    for (int c = 0; c < 16; c++)
        async16(&wlds[c * 256], fragm + c * 256 + l * 4);
    asm volatile("s_waitcnt vmcnt(0)" ::: "memory");

    int hs[16];
    #pragma unroll
    for (int i = 0; i < 16; i++) hs[i] = 0;

    float cst = 0.f;
    const long od = dir ? -(long)os : (long)os;
    const size_t obase = (size_t)ch * T * os
                       + (size_t)(dir ? (L - 1) : 0) * os + dir * 64 + l;
    float* orow_f = (float*)out + obase;
    ushort* orow_h = (ushort*)out + obase;

    auto ld = [&](int s) -> uint2 {
        int tc = (s < L) ? s : (L - 1);
        int t = dir ? (L - 1 - tc) : tc;
        return *(const uint2*)(projc + (size_t)t * 512 + 4 * l);
    };
    uint2 P0 = ld(0), P1 = ld(1), P2 = ld(2);

    for (int s = 0; s < L; s++) {
        int ai0 = 0, ai1 = 0, af0 = 0, af1 = 0;
        int ag0 = 0, ag1 = 0, ao0 = 0, ao1 = 0;
        #pragma unroll
        for (int c = 0; c < 4; c++) {
            uint4 wi = *(const uint4*)&wlds[(0  + c) * 256 + l * 4];
            uint4 wf = *(const uint4*)&wlds[(4  + c) * 256 + l * 4];
            uint4 wg = *(const uint4*)&wlds[(8  + c) * 256 + l * 4];
            uint4 wo = *(const uint4*)&wlds[(12 + c) * 256 + l * 4];
            const int h0 = hs[c * 4 + 0], h1 = hs[c * 4 + 1];
            const int h2 = hs[c * 4 + 2], h3 = hs[c * 4 + 3];
            ai0 = SDOT4(wi.x, h0, ai0); ai1 = SDOT4(wi.y, h1, ai1);
            ai0 = SDOT4(wi.z, h2, ai0); ai1 = SDOT4(wi.w, h3, ai1);
            af0 = SDOT4(wf.x, h0, af0); af1 = SDOT4(wf.y, h1, af1);
            af0 = SDOT4(wf.z, h2, af0); af1 = SDOT4(wf.w, h3, af1);
            ag0 = SDOT4(wg.x, h0, ag0); ag1 = SDOT4(wg.y, h1, ag1);
            ag0 = SDOT4(wg.z, h2, ag0); ag1 = SDOT4(wg.w, h3, ag1);
            ao0 = SDOT4(wo.x, h0, ao0); ao1 = SDOT4(wo.y, h1, ao1);
            ao0 = SDOT4(wo.z, h2, ao0); ao1 = SDOT4(wo.w, h3, ao1);
        }
        const float pi = __uint_as_float(P0.x << 16);
        const float pf = __uint_as_float(P0.x & 0xffff0000u);
        const float pg = __uint_as_float(P0.y << 16);
        const float po = __uint_as_float(P0.y & 0xffff0000u);
        const float iv = fast_sig(fmaf((float)(ai0 + ai1), ks.x, pi));
        const float fv = fast_sig(fmaf((float)(af0 + af1), ks.y, pf));
        const float gv = fast_tanh(fmaf((float)(ag0 + ag1), ks.z, pg));
        const float ov = fast_sig(fmaf((float)(ao0 + ao1), ks.w, po));
        cst = fmaf(fv, cst, iv * gv);
        const float hv = ov * fast_tanh(cst);

        if (OBF) { *orow_h = f2bf(hv); orow_h += od; }
        else     { *orow_f = hv;       orow_f += od; }

        // h -> int8, pack 4 lanes/dword via 2 DPP quad_perm swaps (VALU pipe),
        // then 16 readlane -> SGPR broadcast
        int q8 = __float2int_rn(hv * 127.f);
        int b = q8 & 0xff;
        int t1 = dpp_xor1(b);
        int v01 = (l & 1) ? (t1 | (b << 8)) : (b | (t1 << 8));
        int t2 = dpp_xor2(v01);
        int v0123 = (l & 2) ? ((t2 & 0xffff) | (v01 << 16))
                            : ((v01 & 0xffff) | (t2 << 16));
        #pragma unroll
        for (int i = 0; i < 16; i++)
            hs[i] = __builtin_amdgcn_readlane(v0123, 4 * i);

        P0 = P1; P1 = P2; P2 = ld(s + 3);
    }

    // zero-fill masked region t in [L, T), this direction's 64 cols
    if (OBF) {
        ushort* ob = (ushort*)out + (size_t)ch * T * os + dir * 64;
        for (int idx = l; idx < (T - L) * 64; idx += 64) {
            int t = L + (idx >> 6);
            ob[(size_t)t * os + (idx & 63)] = 0;
        }
    } else {
        float* ob = (float*)out + (size_t)ch * T * os + dir * 64;
        for (int idx = l; idx < (T - L) * 64; idx += 64) {
            int t = L + (idx >> 6);
            ob[(size_t)t * os + (idx & 63)] = 0.f;
        }
    }
}

// fused dual-segment scans (scan||scan: both latency-bound 64-thread waves):
// bx < nA -> segment A (question), else B (header). grid.y = direction.
template<int OBFA, int OBFB>
__global__ __launch_bounds__(64, 1) void scan_fused_kernel(
    int nA,
    const ushort* projA, const uint* fAf, const uint* fAb,
    const float* kAf, const float* kAb, const int* lenA, void* outA, int TA, int osA,
    const ushort* projB, const uint* fBf, const uint* fBb,
    const float* kBf, const float* kBb, const int* lenB, void* outB, int TB, int osB)
{
    __shared__ __align__(16) uint wlds[4096];
    const int bx = blockIdx.x, dir = blockIdx.y;
    if (bx < nA)
        scan_core<OBFA>(projA, fAf, fAb, kAf, kAb, lenA, outA, TA, osA, bx, dir, wlds);
    else
        scan_core<OBFB>(projB, fBf, fBb, kBf, kBb, lenB, outB, TB, osB, bx - nA, dir, wlds);
}

// ---------------- one-hot + zero pad into A_pad cols 128..191 (bf16) ----------------
__global__ __launch_bounds__(256) void onehot_pad_kernel(
    const int* __restrict__ knowledge, ushort* __restrict__ A_pad)
{
    int row = blockIdx.x * 256 + threadIdx.x;
    if (row >= 96 * 512) return;
    int kn = knowledge[row];
    uint words[8] = {0, 0, 0, 0, 0, 0, 0, 0};
    words[kn >> 1] = (kn & 1) ? 0x3F800000u : 0x00003F80u;   // bf16 1.0
    uint4* dst = (uint4*)(A_pad + (size_t)row * 192 + 128);
    dst[0] = make_uint4(words[0], words[1], words[2], words[3]);
    dst[1] = make_uint4(words[4], words[5], words[6], words[7]);
    uint4 z = make_uint4(0, 0, 0, 0);
    dst[2] = z; dst[3] = z; dst[4] = z; dst[5] = z; dst[6] = z; dst[7] = z;
}

// ---------------- header select + gather: wenc_hs in smem -> hs_ob ----------------
__global__ __launch_bounds__(256) void hs_merge_kernel(
    const float* __restrict__ h1_head, const int* __restrict__ l_hpu,
    const int* __restrict__ knowledge_header,
    const int* __restrict__ wc, const int* __restrict__ wn,
    float* __restrict__ hs_ob)
{
    int b = blockIdx.x, tid = threadIdx.x;
    __shared__ float whs[16][132];
    for (int idx = tid; idx < 16 * 132; idx += 256) {
        int u = idx / 132, c = idx - u * 132;
        int g = b * 16 + u;
        int L = l_hpu[g];
        float v;
        if (c < 128) v = h1_head[((size_t)g * 8 + (L - 1)) * 128 + c];
        else v = ((c - 128) == knowledge_header[g]) ? 1.f : 0.f;
        whs[u][c] = v;
    }
    __syncthreads();
    for (int idx = tid; idx < 4 * 132; idx += 256) {
        int w = idx / 132, c = idx - w * 132;
        int col = (w < wn[b]) ? wc[b * 4 + w] : 0;
        hs_ob[((size_t)b * 4 + w) * 132 + c] = whs[col][c];
    }
}

// ------- fused attention: scores(attx) -> softmax -> context(A_pad) -> vec -------
__global__ __launch_bounds__(256) void att_vec_kernel(
    const float* __restrict__ attx, const float* __restrict__ hs_ob,
    const ushort* __restrict__ A_pad, const int* __restrict__ l_n,
    const float* __restrict__ Wc_w, const float* __restrict__ Wc_b,
    const float* __restrict__ Whs_w, const float* __restrict__ Whs_b,
    const float* __restrict__ Wop_w, const float* __restrict__ Wop_b,
    const int* __restrict__ wn, const int* __restrict__ wo,
    float* __restrict__ vec)
{
    int b = blockIdx.x, w = blockIdx.y;
    int tid = threadIdx.x;
    int L = l_n[b];
    __shared__ float q[132];
    __shared__ float sc[512];
    __shared__ float red[256];
    __shared__ float cn[140];
    if (tid < 132) q[tid] = hs_ob[((size_t)b * 4 + w) * 132 + tid];
    __syncthreads();
    for (int t = tid; t < 512; t += 256) {
        float s = -1e30f;
        if (t < L) {
            const float* ax = attx + ((size_t)b * 512 + t) * 132;
            float s0 = 0.f, s1 = 0.f, s2 = 0.f, s3 = 0.f;
            #pragma unroll
            for (int d = 0; d < 132; d += 4) {
                s0 = fmaf(ax[d + 0], q[d + 0], s0);
                s1 = fmaf(ax[d + 1], q[d + 1], s1);
                s2 = fmaf(ax[d + 2], q[d + 2], s2);
                s3 = fmaf(ax[d + 3], q[d + 3], s3);
            }
            s = (s0 + s1) + (s2 + s3);
        }
        sc[t] = s;
    }
    __syncthreads();
    red[tid] = fmaxf(sc[tid], sc[tid + 256]);
    __syncthreads();
    for (int off = 128; off > 0; off >>= 1) {
        if (tid < off) red[tid] = fmaxf(red[tid], red[tid + off]);
        __syncthreads();
    }
    float m = red[0];
    __syncthreads();
    float ps = 0.f;
    for (int t = tid; t < 512; t += 256) {
        float e = (t < L) ? __expf(sc[t] - m) : 0.f;
        sc[t] = e;
        ps += e;
    }
    red[tid] = ps;
    __syncthreads();
    for (int off = 128; off > 0; off >>= 1) {
        if (tid < off) red[tid] += red[tid + off];
        __syncthreads();
    }
    float inv = 1.f / red[0];
    if (tid < 140) {
        float acc = 0.f;
        const ushort* col = A_pad + (size_t)b * 512 * 192 + tid;
        for (int t = 0; t < L; t++)
            acc = fmaf(sc[t], __uint_as_float((uint)col[(size_t)t * 192] << 16), acc);
        cn[tid] = acc * inv;
    }
    __syncthreads();
    float* vrow = vec + ((size_t)b * 4 + w) * 384;
    if (tid < 128) {
        float acc = Wc_b[tid];
        const float* r = Wc_w + (size_t)tid * 140;
        for (int d = 0; d < 140; d++) acc = fmaf(r[d], cn[d], acc);
        vrow[tid] = acc;
    } else {
        int jj = tid - 128;
        float acc = Whs_b[jj];
        const float* r = Whs_w + (size_t)jj * 132;
        for (int d = 0; d < 132; d++) acc = fmaf(r[d], q[d], acc);
        vrow[128 + jj] = acc;
    }
    if (tid < 128) {
        int op = (w < wn[b]) ? wo[b * 4 + w] : 0;
        vrow[256 + tid] = Wop_b[tid] + Wop_w[tid * 4 + op];
    }
}

// ---------------- SIMT GEMM (vpart): C = A @ B^T (+bias) ----------------
__global__ __launch_bounds__(256) void gemm_bias_kernel(
    const float* __restrict__ A, const float* __restrict__ B,
    const float* __restrict__ bias, float* __restrict__ C,
    int M, int N, int K, int lda, int ldb, int ldc)
{
    __shared__ float As[16][68];
    __shared__ float Bs[16][68];
    const int tid = threadIdx.x;
    const int bm = blockIdx.y * 64;
    const int bn = blockIdx.x * 64;
    const int tx = tid & 15;
    const int ty = tid >> 4;
    const int lm = tid & 63;
    const int lk = (tid >> 6) << 2;
    float acc[4][4] = {};
    const int arow = bm + lm;
    const int brow = bn + lm;

    for (int k0 = 0; k0 < K; k0 += 16) {
        int k = k0 + lk;
        float4 av = make_float4(0.f, 0.f, 0.f, 0.f);
        float4 bv = make_float4(0.f, 0.f, 0.f, 0.f);
        if (arow < M) {
            if (k + 4 <= K) av = *(const float4*)(A + (size_t)arow * lda + k);
            else { float* p = (float*)&av;
                for (int i = 0; i < 4; i++) if (k + i < K) p[i] = A[(size_t)arow * lda + k + i]; }
        }
        if (brow < N) {
            if (k + 4 <= K) bv = *(const float4*)(B + (size_t)brow * ldb + k);
            else { float* p = (float*)&bv;
                for (int i = 0; i < 4; i++) if (k + i < K) p[i] = B[(size_t)brow * ldb + k + i]; }
        }
        As[lk + 0][lm] = av.x; As[lk + 1][lm] = av.y; As[lk + 2][lm] = av.z; As[lk + 3][lm] = av.w;
        Bs[lk + 0][lm] = bv.x; Bs[lk + 1][lm] = bv.y; Bs[lk + 2][lm] = bv.z; Bs[lk + 3][lm] = bv.w;
        __syncthreads();
        #pragma unroll
        for (int kk = 0; kk < 16; kk++) {
            float a[4], bb[4];
            #pragma unroll
            for (int i = 0; i < 4; i++) a[i] = As[kk][ty * 4 + i];
            #pragma unroll
            for (int j = 0; j < 4; j++) bb[j] = Bs[kk][tx * 4 + j];
            #pragma unroll
            for (int i = 0; i < 4; i++)
                #pragma unroll
                for (int j = 0; j < 4; j++)
                    acc[i][j] = fmaf(a[i], bb[j], acc[i][j]);
        }
        __syncthreads();
    }
    #pragma unroll
    for (int i = 0; i < 4; i++) {
        int row = bm + ty * 4 + i;
        if (row >= M) continue;
        #pragma unroll
        for (int j = 0; j < 4; j++) {
            int col = bn + tx * 4 + j;
            if (col < N) C[(size_t)row * ldc + col] = acc[i][j] + (bias ? bias[col] : 0.f);
        }
    }
}

// ---------------- final: out[b,w,t,:] = tanh(vpart+npart)@out2.T + b, masked ----------------
__global__ __launch_bounds__(256) void final_kernel(
    const float* __restrict__ vpart, const float* __restrict__ npart,
    const float* __restrict__ out2_w, const float* __restrict__ out2_b,
    const int* __restrict__ l_n, float* __restrict__ out)
{
    int b = blockIdx.y;
    int tid = threadIdx.x;
    int t = blockIdx.x * 256 + tid;
    __shared__ float vp[512];
    __shared__ float w2[256];
    w2[tid] = out2_w[tid];
    for (int i = tid; i < 512; i += 256) vp[i] = vpart[(size_t)b * 512 + i];
    __syncthreads();
    int L = l_n[b];
    float s[4][2];
    if (t < L) {
        float b0 = out2_b[0], b1 = out2_b[1];
        #pragma unroll
        for (int w = 0; w < 4; w++) { s[w][0] = b0; s[w][1] = b1; }
        const float4* np4 = (const float4*)(npart + ((size_t)b * 512 + t) * 128);
        for (int h4 = 0; h4 < 32; h4++) {
            float4 n = np4[h4];
            const float* nf = (const float*)&n;
            #pragma unroll
            for (int e = 0; e < 4; e++) {
                int h = h4 * 4 + e;
                float nv = nf[e];
                float w0 = w2[h], w1 = w2[128 + h];
                #pragma unroll
                for (int w = 0; w < 4; w++) {
                    float z = fast_tanh(vp[w * 128 + h] + nv);
                    s[w][0] = fmaf(z, w0, s[w][0]);
                    s[w][1] = fmaf(z, w1, s[w][1]);
                }
            }
        }
    } else {
        #pragma unroll
        for (int w = 0; w < 4; w++) { s[w][0] = NEGV; s[w][1] = NEGV; }
    }
    #pragma unroll
    for (int w = 0; w < 4; w++) {
        size_t o = (((size_t)b * 4 + w) * 512 + t) * 2;
        out[o + 0] = s[w][0];
        out[o + 1] = s[w][1];
    }
}

// ---------------------------------------------------------------------------
extern "C" void kernel_launch(void* const* d_in, const int* in_sizes, int n_in,
                              void* d_out, int out_size, void* d_ws, size_t ws_size,
                              hipStream_t stream)
{
    const float* wemb_n   = (const float*)d_in[0];
    const float* wemb_hpu = (const float*)d_in[1];
    const float* Wih_n0f = (const float*)d_in[2];
    const float* Whh_n0f = (const float*)d_in[3];
    const float* b_n0f   = (const float*)d_in[4];
    const float* Wih_n0b = (const float*)d_in[5];
    const float* Whh_n0b = (const float*)d_in[6];
    const float* b_n0b   = (const float*)d_in[7];
    const float* Wih_n1f = (const float*)d_in[8];
    const float* Whh_n1f = (const float*)d_in[9];
    const float* b_n1f   = (const float*)d_in[10];
    const float* Wih_n1b = (const float*)d_in[11];
    const float* Whh_n1b = (const float*)d_in[12];
    const float* b_n1b   = (const float*)d_in[13];
    const float* Wih_h0f = (const float*)d_in[14];
    const float* Whh_h0f = (const float*)d_in[15];
    const float* b_h0f   = (const float*)d_in[16];
    const float* Wih_h0b = (const float*)d_in[17];
    const float* Whh_h0b = (const float*)d_in[18];
    const float* b_h0b   = (const float*)d_in[19];
    const float* Wih_h1f = (const float*)d_in[20];
    const float* Whh_h1f = (const float*)d_in[21];
    const float* b_h1f   = (const float*)d_in[22];
    const float* Wih_h1b = (const float*)d_in[23];
    const float* Whh_h1b = (const float*)d_in[24];
    const float* b_h1b   = (const float*)d_in[25];
    const float* Watt_w  = (const float*)d_in[26];
    const float* Watt_b  = (const float*)d_in[27];
    const float* Wc_w    = (const float*)d_in[28];
    const float* Wc_b    = (const float*)d_in[29];
    const float* Whs_w   = (const float*)d_in[30];
    const float* Whs_b   = (const float*)d_in[31];
    const float* Wop_w   = (const float*)d_in[32];
    const float* Wop_b   = (const float*)d_in[33];
    const float* out1_w  = (const float*)d_in[34];
    const float* out1_b  = (const float*)d_in[35];
    const float* out2_w  = (const float*)d_in[36];
    const float* out2_b  = (const float*)d_in[37];
    const int* l_n   = (const int*)d_in[38];
    const int* l_hpu = (const int*)d_in[39];
    const int* wc    = (const int*)d_in[40];
    const int* wn    = (const int*)d_in[41];
    const int* wo    = (const int*)d_in[42];
    const int* knowledge        = (const int*)d_in[43];
    const int* knowledge_header = (const int*)d_in[44];

    float* ws = (float*)d_ws;
    // ---- workspace map (float offsets; lifetimes annotated) ----
    ushort* proj_q  = (ushort*)(ws + 0);          // [0,12582912)  49152x512 bf16
    ushort* proj_h  = (ushort*)(ws + 12582912);   // [12582912,15728640) 12288x512 bf16
    ushort* AbfH0   = (ushort*)(ws + 15728640);   // wemb_hpu bf16 (dead after G0)
    ushort* A_pad   = (ushort*)(ws + 15728640);   // [49152][192] bf16 (written post-G0)
    ushort* Bp_att  = (ushort*)(ws + 20447232);   // 256x192
    ushort* Bp_out  = (ushort*)(ws + 20471808);   // 128x192
    float*  bias_pad = ws + 20484096;             // 256
    ushort* h_h0_bf = (ushort*)(ws + 22057216);   // 12288x128 bf16
    ushort* WbfQ0   = (ushort*)(ws + 22843648);   // 512x512 bf16
    ushort* WbfH0   = (ushort*)(ws + 22974720);
    ushort* WbfQ1   = (ushort*)(ws + 23105792);   // 512x128
    ushort* WbfH1   = (ushort*)(ws + 23138560);
    uint*   frag8   = (uint*)(ws + 23171328);     // 8 x 4096 dwords int8 Whh (LDS-tiled)
    float*  ksc     = ws + 23204096;              // 8 x 256 scales
    float*  bias_all = ws + 23236864;             // [4][512]
    ushort* AbfQ0   = (ushort*)(ws + 25165824);   // wemb_n bf16 (dead after G0)
    float*  h1_head = ws + 26738688;              // 12288x128 fp32 (post-G0)
    ushort* wenc0_bf = (ushort*)(ws + 31457280);  // 49152x128 bf16 (post-G0)
    float*  attx    = ws + 0;                     // reuse proj_q after QS1
    float*  npart   = ws + 6488064;               // [6488064,12779520)
    float*  hs_ob   = ws + 38541312;
    float*  vec     = ws + 38645760;
    float*  vpart   = ws + 38793216;
    float*  outp    = (float*)d_out;

    dim3 blk(256);
    auto cast2 = [&](const float* a, const float* b, ushort* oa, ushort* ob, int na, int nb) {
        cast2_bf16_kernel<<<dim3(((na + nb) / 8 + 255) / 256), blk, 0, stream>>>(a, b, oa, ob, na, nb);
    };

    // ---- prep + casts ----
    prep_all_kernel<<<dim3(401), blk, 0, stream>>>(
        Whh_n0f, Whh_n0b, Whh_n1f, Whh_n1b, Whh_h0f, Whh_h0b, Whh_h1f, Whh_h1b,
        frag8, ksc,
        b_n0f, b_n0b, b_n1f, b_n1b, b_h0f, b_h0b, b_h1f, b_h1b, bias_all,
        Watt_w, Bp_att, out1_w, Bp_out, Watt_b, bias_pad);
    cast2(wemb_n, wemb_hpu, AbfQ0, AbfH0, 96 * 512 * 512, 1536 * 8 * 512);
    cast2(Wih_n0f, Wih_n0b, WbfQ0, WbfQ0 + 256 * 512, 256 * 512, 256 * 512);
    cast2(Wih_h0f, Wih_h0b, WbfH0, WbfH0 + 256 * 512, 256 * 512, 256 * 512);
    cast2(Wih_n1f, Wih_n1b, WbfQ1, WbfQ1 + 256 * 128, 256 * 128, 256 * 128);
    cast2(Wih_h1f, Wih_h1b, WbfH1, WbfH1 + 256 * 128, 256 * 128, 256 * 128);

    // ---- layer 0 projections (QG0 + HG0 in one dispatch) ----
    gemm_dual_kernel<<<dim3(4, 480), blk, 0, stream>>>(
        AbfQ0, WbfQ0, bias_all + 0 * 512, proj_q, 384,
        AbfH0, WbfH0, bias_all + 2 * 512, proj_h,
        512, 512, 512, 2);
    onehot_pad_kernel<<<dim3(192), blk, 0, stream>>>(knowledge, A_pad);

    // ---- layer-0 scans: QS0 || HS0 fused ----
    scan_fused_kernel<1, 1><<<dim3(96 + 1536, 2), dim3(64), 0, stream>>>(
        96,
        proj_q, frag8 + 0 * 4096, frag8 + 1 * 4096, ksc + 0 * 256, ksc + 1 * 256,
        l_n, wenc0_bf, 512, 128,
        proj_h, frag8 + 4 * 4096, frag8 + 5 * 4096, ksc + 4 * 256, ksc + 5 * 256,
        l_hpu, h_h0_bf, 8, 128);

    // ---- layer 1 projections (QG1 + HG1 in one dispatch) ----
    gemm_dual_kernel<<<dim3(4, 480), blk, 0, stream>>>(
        wenc0_bf, WbfQ1, bias_all + 1 * 512, proj_q, 384,
        h_h0_bf, WbfH1, bias_all + 3 * 512, proj_h,
        128, 512, 512, 2);

    // ---- layer-1 scans: QS1 (A_pad bf16, stride 192) || HS1 (fp32) fused ----
    scan_fused_kernel<1, 0><<<dim3(96 + 1536, 2), dim3(64), 0, stream>>>(
        96,
        proj_q, frag8 + 2 * 4096, frag8 + 3 * 4096, ksc + 2 * 256, ksc + 3 * 256,
        l_n, A_pad, 512, 192,
        proj_h, frag8 + 6 * 4096, frag8 + 7 * 4096, ksc + 6 * 256, ksc + 7 * 256,
        l_hpu, h1_head, 8, 128);

    // ---- tail ----
    hs_merge_kernel<<<dim3(96), blk, 0, stream>>>(h1_head, l_hpu, knowledge_header,
                                                  wc, wn, hs_ob);
    gemm_pair_kernel<<<dim3(3, 384), blk, 0, stream>>>(
        A_pad, Bp_att, bias_pad, attx, Bp_out, npart, 192);
    att_vec_kernel<<<dim3(96, 4), blk, 0, stream>>>(attx, hs_ob, A_pad, l_n,
                                                    Wc_w, Wc_b, Whs_w, Whs_b,
                                                    Wop_w, Wop_b, wn, wo, vec);
    gemm_bias_kernel<<<dim3(2, 6), blk, 0, stream>>>(vec, out1_w, out1_b, vpart,
                                                     384, 128, 384, 384, 524, 128);
    final_kernel<<<dim3(2, 96), blk, 0, stream>>>(vpart, npart, out2_w, out2_b, l_n, outp);
}

// Round 19
// 613.648 us; speedup vs baseline: 1.5673x; 1.0695x over previous
//
#include <hip/hip_runtime.h>
#include <math.h>

#define NEGV -1e10f

typedef __bf16 bf16x8 __attribute__((ext_vector_type(8)));
typedef float f32x4 __attribute__((ext_vector_type(4)));
typedef unsigned short ushort;
typedef unsigned int uint;

__device__ __forceinline__ float fast_tanh(float x) {
    float e = __expf(2.0f * x);
    return fmaf(-2.f, __builtin_amdgcn_rcpf(e + 1.f), 1.f);
}
__device__ __forceinline__ float fast_sig(float x) {
    return __builtin_amdgcn_rcpf(1.f + __expf(-x));
}
__device__ __forceinline__ ushort f2bf(float x) {
    unsigned int b = __float_as_uint(x);
    b += 0x7fffu + ((b >> 16) & 1u);   // RNE
    return (ushort)(b >> 16);
}
#if __has_builtin(__builtin_amdgcn_sdot4)
#define SDOT4(a, b, c) __builtin_amdgcn_sdot4((int)(a), (int)(b), (int)(c), false)
#else
__device__ __forceinline__ int SDOT4(int a, int b, int c) {
    #pragma unroll
    for (int k = 0; k < 4; k++) {
        int xa = (a >> (8 * k)) & 0xff; xa = (xa ^ 0x80) - 0x80;
        int xb = (b >> (8 * k)) & 0xff; xb = (xb ^ 0x80) - 0x80;
        c += xa * xb;
    }
    return c;
}
#endif
// VALU-pipe lane swaps within quads: quad_perm[1,0,3,2]=0xB1 (lane^1),
// quad_perm[2,3,0,1]=0x4E (lane^2)
__device__ __forceinline__ int dpp_xor1(int v) {
    return __builtin_amdgcn_update_dpp(0, v, 0xB1, 0xf, 0xf, true);
}
__device__ __forceinline__ int dpp_xor2(int v) {
    return __builtin_amdgcn_update_dpp(0, v, 0x4E, 0xf, 0xf, true);
}
// async 16B global -> LDS (dest = wave-uniform base + lane*16, src per-lane)
__device__ __forceinline__ void async16(void* l, const void* g) {
    __builtin_amdgcn_global_load_lds(
        (const __attribute__((address_space(1))) void*)g,
        (__attribute__((address_space(3))) void*)l,
        16, 0, 0);
}

// ---------------- multi-segment fp32 -> bf16 cast (all n % 8 == 0) ----------------
__global__ __launch_bounds__(256) void cast_multi_kernel(
    const float* s0, ushort* d0, int n0,
    const float* s1, ushort* d1, int n1,
    const float* s2, ushort* d2, int n2,
    const float* s3, ushort* d3, int n3,
    const float* s4, ushort* d4, int n4,
    const float* s5, ushort* d5, int n5,
    const float* s6, ushort* d6, int n6,
    const float* s7, ushort* d7, int n7,
    const float* s8, ushort* d8, int n8,
    const float* s9, ushort* d9, int n9)
{
    long i = ((long)blockIdx.x * 256 + threadIdx.x) * 8;
    const float* s; ushort* d;
    if (i < n0) { s = s0; d = d0; }
    else { i -= n0;
    if (i < n1) { s = s1; d = d1; }
    else { i -= n1;
    if (i < n2) { s = s2; d = d2; }
    else { i -= n2;
    if (i < n3) { s = s3; d = d3; }
    else { i -= n3;
    if (i < n4) { s = s4; d = d4; }
    else { i -= n4;
    if (i < n5) { s = s5; d = d5; }
    else { i -= n5;
    if (i < n6) { s = s6; d = d6; }
    else { i -= n6;
    if (i < n7) { s = s7; d = d7; }
    else { i -= n7;
    if (i < n8) { s = s8; d = d8; }
    else { i -= n8;
    if (i < n9) { s = s9; d = d9; }
    else return; }}}}}}}}}
    float4 a = *(const float4*)(s + i);
    float4 b = *(const float4*)(s + i + 4);
    uint4 o;
    o.x = (unsigned)f2bf(a.x) | ((unsigned)f2bf(a.y) << 16);
    o.y = (unsigned)f2bf(a.z) | ((unsigned)f2bf(a.w) << 16);
    o.z = (unsigned)f2bf(b.x) | ((unsigned)f2bf(b.y) << 16);
    o.w = (unsigned)f2bf(b.z) | ((unsigned)f2bf(b.w) << 16);
    *(uint4*)(d + i) = o;
}

// ============ prep_all: whh-int8 pack | bias concat | Bp_att | Bp_out | bias_pad ============
__global__ __launch_bounds__(256) void prep_all_kernel(
    const float* W0, const float* W1, const float* W2, const float* W3,
    const float* W4, const float* W5, const float* W6, const float* W7,
    uint* __restrict__ frag8, float* __restrict__ ksc,
    const float* s0, const float* s1, const float* s2, const float* s3,
    const float* s4, const float* s5, const float* s6, const float* s7,
    float* __restrict__ bias_all,
    const float* __restrict__ Watt_w, ushort* __restrict__ Bp_att,
    const float* __restrict__ out1_w, ushort* __restrict__ Bp_out,
    const float* __restrict__ Watt_b, float* __restrict__ bias_pad)
{
    const int bx = blockIdx.x, tid = threadIdx.x;
    if (bx < 8) {
        const float* Ws[8] = {W0, W1, W2, W3, W4, W5, W6, W7};
        const float* W = Ws[bx];
        int l = tid >> 2, g = tid & 3;
        const float* row = W + (size_t)(g * 64 + l) * 64;
        float amax = 0.f;
        for (int k = 0; k < 64; k++) amax = fmaxf(amax, fabsf(row[k]));
        float sw = fmaxf(amax, 1e-12f) / 127.f;
        float inv = 127.f / fmaxf(amax, 1e-12f);
        ksc[bx * 256 + l * 4 + g] = sw / 127.f;
        for (int jj = 0; jj < 16; jj++) {
            uint wd = 0;
            #pragma unroll
            for (int k = 0; k < 4; k++) {
                int q = __float2int_rn(row[4 * jj + k] * inv);
                q = max(-127, min(127, q));
                wd |= ((uint)(q & 0xff)) << (8 * k);
            }
            int j = g * 16 + jj;
            frag8[bx * 4096 + (j >> 2) * 256 + l * 4 + (j & 3)] = wd;
        }
    } else if (bx < 16) {
        const float* srcs[8] = {s0, s1, s2, s3, s4, s5, s6, s7};
        bias_all[(bx - 8) * 256 + tid] = srcs[bx - 8][tid];
    } else if (bx < 272) {
        int rowi = bx - 16;
        if (tid < 96) {
            float a = 0.f, b = 0.f;
            if (rowi < 132) {
                const float* s = Watt_w + (size_t)rowi * 140;
                if (2 * tid < 140) a = s[2 * tid];
                if (2 * tid + 1 < 140) b = s[2 * tid + 1];
            }
            ((uint*)(Bp_att + (size_t)rowi * 192))[tid] =
                (uint)f2bf(a) | ((uint)f2bf(b) << 16);
        }
    } else if (bx < 400) {
        int rowi = bx - 272;
        if (tid < 96) {
            const float* s = out1_w + (size_t)rowi * 524 + 384;
            float a = (2 * tid < 140) ? s[2 * tid] : 0.f;
            float b = (2 * tid + 1 < 140) ? s[2 * tid + 1] : 0.f;
            ((uint*)(Bp_out + (size_t)rowi * 192))[tid] =
                (uint)f2bf(a) | ((uint)f2bf(b) << 16);
        }
    } else {
        bias_pad[tid] = (tid < 132) ? Watt_b[tid] : 0.f;
    }
}

// =============== shared MFMA GEMM core: C = A[.,K]bf16 @ B[.,K]bf16^T (+bias) ===============
// mode 1: fp32 store, cols < Nstore. mode 2: bf16 store, scan-perm layout
// (col = dir*256+g*64+u -> dir*256 + u*4 + g), ldc elements.
__device__ __forceinline__ void gemm_core(
    const ushort* __restrict__ A, const ushort* __restrict__ B,
    const float* __restrict__ bias, void* __restrict__ C,
    int K, int ldc, int Nstore, int mode, int bm, int bn, ushort* lds)
{
    ushort* ldsA = lds;
    ushort* ldsB = lds + 8192;
    const int tid = threadIdx.x;
    const int wv = tid >> 6, ln = tid & 63;
    const int r15 = ln & 15, r4 = ln >> 4;

    f32x4 acc[4][4] = {};

    for (int k0 = 0; k0 < K; k0 += 64) {
        #pragma unroll
        for (int c4 = 0; c4 < 4; c4++) {
            const int c = c4 * 4 + wv;
            const int s = c * 64 + ln;
            const int rt = s >> 3;
            const int ce = ((s & 7) ^ (rt & 7)) * 8;   // T2 swizzle (both sides)
            async16(&ldsA[c * 512], A + (size_t)(bm + rt) * K + k0 + ce);
            async16(&ldsB[c * 512], B + (size_t)(bn + rt) * K + k0 + ce);
        }
        __syncthreads();
        const int mr = (wv >> 1) * 64, nc = (wv & 1) * 64;
        #pragma unroll
        for (int kk = 0; kk < 2; kk++) {
            bf16x8 af[4], bfr[4];
            #pragma unroll
            for (int m = 0; m < 4; m++) {
                const int r = mr + m * 16 + r15;
                const int off = r * 128 + ((kk * 64 + r4 * 16) ^ ((r & 7) << 4));
                af[m] = *(const bf16x8*)((const char*)ldsA + off);
            }
            #pragma unroll
            for (int n = 0; n < 4; n++) {
                const int r = nc + n * 16 + r15;
                const int off = r * 128 + ((kk * 64 + r4 * 16) ^ ((r & 7) << 4));
                bfr[n] = *(const bf16x8*)((const char*)ldsB + off);
            }
            #pragma unroll
            for (int m = 0; m < 4; m++)
                #pragma unroll
                for (int n = 0; n < 4; n++)
                    acc[m][n] = __builtin_amdgcn_mfma_f32_16x16x32_bf16(
                        af[m], bfr[n], acc[m][n], 0, 0, 0);
        }
        __syncthreads();
    }
    const int mro = bm + (wv >> 1) * 64, nco = bn + (wv & 1) * 64;
    #pragma unroll
    for (int m = 0; m < 4; m++) {
        #pragma unroll
        for (int n = 0; n < 4; n++) {
            const int col = nco + n * 16 + r15;
            const float bs = bias ? bias[col] : 0.f;
            if (mode == 2) {
                const int cout = (col >> 8) * 256 + (col & 63) * 4 + ((col >> 6) & 3);
                #pragma unroll
                for (int r = 0; r < 4; r++) {
                    const int row = mro + m * 16 + r4 * 4 + r;
                    ((ushort*)C)[(size_t)row * ldc + cout] = f2bf(acc[m][n][r] + bs);
                }
            } else if (col < Nstore) {
                #pragma unroll
                for (int r = 0; r < 4; r++) {
                    const int row = mro + m * 16 + r4 * 4 + r;
                    ((float*)C)[(size_t)row * ldc + col] = acc[m][n][r] + bs;
                }
            }
        }
    }
}

// dual-segment GEMM: blockIdx.y < My0 -> segment 0, else segment 1
__global__ __launch_bounds__(256) void gemm_dual_kernel(
    const ushort* A0, const ushort* B0, const float* b0, void* C0, int My0,
    const ushort* A1, const ushort* B1, const float* b1, void* C1,
    int K, int ldc, int Nstore, int mode)
{
    __shared__ __align__(16) ushort smem[16384];
    int by = blockIdx.y;
    if (by < My0)
        gemm_core(A0, B0, b0, C0, K, ldc, Nstore, mode, by * 128, blockIdx.x * 128, smem);
    else
        gemm_core(A1, B1, b1, C1, K, ldc, Nstore, mode, (by - My0) * 128, blockIdx.x * 128, smem);
}

// pair GEMM: bx<2 -> attx (N=132 fp32), bx==2 -> npart (N=128 fp32); shared A
__global__ __launch_bounds__(256) void gemm_pair_kernel(
    const ushort* __restrict__ A,
    const ushort* __restrict__ B0, const float* __restrict__ b0, float* __restrict__ C0,
    const ushort* __restrict__ B1, float* __restrict__ C1, int K)
{
    __shared__ __align__(16) ushort smem[16384];
    if (blockIdx.x < 2)
        gemm_core(A, B0, b0, C0, K, 132, 132, 1, blockIdx.y * 128, blockIdx.x * 128, smem);
    else
        gemm_core(A, B1, nullptr, C1, K, 128, 128, 1, blockIdx.y * 128, 0, smem);
}

// =============== LSTM scan int8 core: one wave per (chain,dir) ===============
// R16 structure (best known): weights staged once into LDS (16KB), re-read each
// step via conflict-free ds_read_b128 on the DS pipe; h-redistribution via DPP
// quad_perm (VALU) + 16 readlanes; proj prefetch depth-3 on VMEM. Per-row int8
// quant, scale ksc[l*4+g].
// proj bf16 [ch][T][dir*256 + u*4 + g]; OBF=1: bf16 out (os elems), else fp32.
template<int OBF>
__device__ __forceinline__ void scan_core(
    const ushort* __restrict__ proj,
    const uint* __restrict__ frag_f, const uint* __restrict__ frag_b,
    const float* __restrict__ ksc_f, const float* __restrict__ ksc_b,
    const int* __restrict__ lengths, void* __restrict__ out,
    int T, int os, int ch, int dir, uint* wlds)
{
    const int l = threadIdx.x;
    const int L = lengths[ch];
    const ushort* projc = proj + (size_t)ch * T * 512 + dir * 256;
    const uint* fragm = dir ? frag_b : frag_f;
    const float4 ks = *(const float4*)((dir ? ksc_b : ksc_f) + l * 4);

    // stage 16KB weights into LDS (chunk-major, lane-consecutive 16B)
    #pragma unroll
    for (int c = 0; c < 16; c++)
        async16(&wlds[c * 256], fragm + c * 256 + l * 4);
    asm volatile("s_waitcnt vmcnt(0)" ::: "memory");

    int hs[16];
    #pragma unroll
    for (int i = 0; i < 16; i++) hs[i] = 0;

    float cst = 0.f;
    const long od = dir ? -(long)os : (long)os;
    const size_t obase = (size_t)ch * T * os
                       + (size_t)(dir ? (L - 1) : 0) * os + dir * 64 + l;
    float* orow_f = (float*)out + obase;
    ushort* orow_h = (ushort*)out + obase;

    auto ld = [&](int s) -> uint2 {
        int tc = (s < L) ? s : (L - 1);
        int t = dir ? (L - 1 - tc) : tc;
        return *(const uint2*)(projc + (size_t)t * 512 + 4 * l);
    };
    uint2 P0 = ld(0), P1 = ld(1), P2 = ld(2);

    for (int s = 0; s < L; s++) {
        int ai0 = 0, ai1 = 0, af0 = 0, af1 = 0;
        int ag0 = 0, ag1 = 0, ao0 = 0, ao1 = 0;
        #pragma unroll
        for (int c = 0; c < 4; c++) {
            uint4 wi = *(const uint4*)&wlds[(0  + c) * 256 + l * 4];
            uint4 wf = *(const uint4*)&wlds[(4  + c) * 256 + l * 4];
            uint4 wg = *(const uint4*)&wlds[(8  + c) * 256 + l * 4];
            uint4 wo = *(const uint4*)&wlds[(12 + c) * 256 + l * 4];
            const int h0 = hs[c * 4 + 0], h1 = hs[c * 4 + 1];
            const int h2 = hs[c * 4 + 2], h3 = hs[c * 4 + 3];
            ai0 = SDOT4(wi.x, h0, ai0); ai1 = SDOT4(wi.y, h1, ai1);
            ai0 = SDOT4(wi.z, h2, ai0); ai1 = SDOT4(wi.w, h3, ai1);
            af0 = SDOT4(wf.x, h0, af0); af1 = SDOT4(wf.y, h1, af1);
            af0 = SDOT4(wf.z, h2, af0); af1 = SDOT4(wf.w, h3, af1);
            ag0 = SDOT4(wg.x, h0, ag0); ag1 = SDOT4(wg.y, h1, ag1);
            ag0 = SDOT4(wg.z, h2, ag0); ag1 = SDOT4(wg.w, h3, ag1);
            ao0 = SDOT4(wo.x, h0, ao0); ao1 = SDOT4(wo.y, h1, ao1);
            ao0 = SDOT4(wo.z, h2, ao0); ao1 = SDOT4(wo.w, h3, ao1);
        }
        const float pi = __uint_as_float(P0.x << 16);
        const float pf = __uint_as_float(P0.x & 0xffff0000u);
        const float pg = __uint_as_float(P0.y << 16);
        const float po = __uint_as_float(P0.y & 0xffff0000u);
        const float iv = fast_sig(fmaf((float)(ai0 + ai1), ks.x, pi));
        const float fv = fast_sig(fmaf((float)(af0 + af1), ks.y, pf));
        const float gv = fast_tanh(fmaf((float)(ag0 + ag1), ks.z, pg));
        const float ov = fast_sig(fmaf((float)(ao0 + ao1), ks.w, po));
        cst = fmaf(fv, cst, iv * gv);
        const float hv = ov * fast_tanh(cst);

        if (OBF) { *orow_h = f2bf(hv); orow_h += od; }
        else     { *orow_f = hv;       orow_f += od; }

        // h -> int8, pack 4 lanes/dword via 2 DPP quad_perm swaps (VALU pipe),
        // then 16 readlane -> SGPR broadcast
        int q8 = __float2int_rn(hv * 127.f);
        int b = q8 & 0xff;
        int t1 = dpp_xor1(b);
        int v01 = (l & 1) ? (t1 | (b << 8)) : (b | (t1 << 8));
        int t2 = dpp_xor2(v01);
        int v0123 = (l & 2) ? ((t2 & 0xffff) | (v01 << 16))
                            : ((v01 & 0xffff) | (t2 << 16));
        #pragma unroll
        for (int i = 0; i < 16; i++)
            hs[i] = __builtin_amdgcn_readlane(v0123, 4 * i);

        P0 = P1; P1 = P2; P2 = ld(s + 3);
    }

    // zero-fill masked region t in [L, T), this direction's 64 cols
    if (OBF) {
        ushort* ob = (ushort*)out + (size_t)ch * T * os + dir * 64;
        for (int idx = l; idx < (T - L) * 64; idx += 64) {
            int t = L + (idx >> 6);
            ob[(size_t)t * os + (idx & 63)] = 0;
        }
    } else {
        float* ob = (float*)out + (size_t)ch * T * os + dir * 64;
        for (int idx = l; idx < (T - L) * 64; idx += 64) {
            int t = L + (idx >> 6);
            ob[(size_t)t * os + (idx & 63)] = 0.f;
        }
    }
}

// fused dual-segment scans (scan||scan: both latency-bound 64-thread waves):
// bx < nA -> segment A (question), else B (header). grid.y = direction.
template<int OBFA, int OBFB>
__global__ __launch_bounds__(64, 1) void scan_fused_kernel(
    int nA,
    const ushort* projA, const uint* fAf, const uint* fAb,
    const float* kAf, const float* kAb, const int* lenA, void* outA, int TA, int osA,
    const ushort* projB, const uint* fBf, const uint* fBb,
    const float* kBf, const float* kBb, const int* lenB, void* outB, int TB, int osB)
{
    __shared__ __align__(16) uint wlds[4096];
    const int bx = blockIdx.x, dir = blockIdx.y;
    if (bx < nA)
        scan_core<OBFA>(projA, fAf, fAb, kAf, kAb, lenA, outA, TA, osA, bx, dir, wlds);
    else
        scan_core<OBFB>(projB, fBf, fBb, kBf, kBb, lenB, outB, TB, osB, bx - nA, dir, wlds);
}

// ---------------- one-hot + zero pad into A_pad cols 128..191 (bf16) ----------------
__global__ __launch_bounds__(256) void onehot_pad_kernel(
    const int* __restrict__ knowledge, ushort* __restrict__ A_pad)
{
    int row = blockIdx.x * 256 + threadIdx.x;
    if (row >= 96 * 512) return;
    int kn = knowledge[row];
    uint words[8] = {0, 0, 0, 0, 0, 0, 0, 0};
    words[kn >> 1] = (kn & 1) ? 0x3F800000u : 0x00003F80u;   // bf16 1.0
    uint4* dst = (uint4*)(A_pad + (size_t)row * 192 + 128);
    dst[0] = make_uint4(words[0], words[1], words[2], words[3]);
    dst[1] = make_uint4(words[4], words[5], words[6], words[7]);
    uint4 z = make_uint4(0, 0, 0, 0);
    dst[2] = z; dst[3] = z; dst[4] = z; dst[5] = z; dst[6] = z; dst[7] = z;
}

// ====== mega-tail: per (b,w): header gather -> scores -> softmax -> context
//        -> vec -> vpart (smem) -> final output rows (tanh + out2) ======
__global__ __launch_bounds__(256) void att_final_kernel(
    const float* __restrict__ attx,
    const float* __restrict__ h1_head, const int* __restrict__ l_hpu,
    const int* __restrict__ knowledge_header,
    const int* __restrict__ wc, const int* __restrict__ wn,
    const ushort* __restrict__ A_pad, const int* __restrict__ l_n,
    const float* __restrict__ Wc_w, const float* __restrict__ Wc_b,
    const float* __restrict__ Whs_w, const float* __restrict__ Whs_b,
    const float* __restrict__ Wop_w, const float* __restrict__ Wop_b,
    const int* __restrict__ wo,
    const float* __restrict__ out1_w, const float* __restrict__ out1_b,
    const float* __restrict__ npart,
    const float* __restrict__ out2_w, const float* __restrict__ out2_b,
    float* __restrict__ out)
{
    int b = blockIdx.x, w = blockIdx.y;
    int tid = threadIdx.x;
    int L = l_n[b];
    __shared__ float q[132];
    __shared__ float sc[512];
    __shared__ float red[256];
    __shared__ float cn[140];
    __shared__ float vs[384];
    __shared__ float vp[128];
    __shared__ float w2[256];

    // header column gather (replaces hs_merge): this block's hs_ob row
    int col = (w < wn[b]) ? wc[b * 4 + w] : 0;
    int g = b * 16 + col;
    if (tid < 132) {
        int Lh = l_hpu[g];
        q[tid] = (tid < 128) ? h1_head[((size_t)g * 8 + (Lh - 1)) * 128 + tid]
                             : (((tid - 128) == knowledge_header[g]) ? 1.f : 0.f);
    }
    w2[tid] = out2_w[tid];
    __syncthreads();

    // scores
    for (int t = tid; t < 512; t += 256) {
        float s = -1e30f;
        if (t < L) {
            const float* ax = attx + ((size_t)b * 512 + t) * 132;
            float s0 = 0.f, s1 = 0.f, s2 = 0.f, s3 = 0.f;
            #pragma unroll
            for (int d = 0; d < 132; d += 4) {
                s0 = fmaf(ax[d + 0], q[d + 0], s0);
                s1 = fmaf(ax[d + 1], q[d + 1], s1);
                s2 = fmaf(ax[d + 2], q[d + 2], s2);
                s3 = fmaf(ax[d + 3], q[d + 3], s3);
            }
            s = (s0 + s1) + (s2 + s3);
        }
        sc[t] = s;
    }
    __syncthreads();
    red[tid] = fmaxf(sc[tid], sc[tid + 256]);
    __syncthreads();
    for (int off = 128; off > 0; off >>= 1) {
        if (tid < off) red[tid] = fmaxf(red[tid], red[tid + off]);
        __syncthreads();
    }
    float m = red[0];
    __syncthreads();
    float ps = 0.f;
    for (int t = tid; t < 512; t += 256) {
        float e = (t < L) ? __expf(sc[t] - m) : 0.f;
        sc[t] = e;
        ps += e;
    }
    red[tid] = ps;
    __syncthreads();
    for (int off = 128; off > 0; off >>= 1) {
        if (tid < off) red[tid] += red[tid + off];
        __syncthreads();
    }
    float inv = 1.f / red[0];
    // context over A_pad cols (x4-unrolled independent accumulators)
    if (tid < 140) {
        float a0 = 0.f, a1 = 0.f, a2 = 0.f, a3 = 0.f;
        const ushort* colp = A_pad + (size_t)b * 512 * 192 + tid;
        int t = 0;
        for (; t + 4 <= L; t += 4) {
            a0 = fmaf(sc[t + 0], __uint_as_float((uint)colp[(size_t)(t + 0) * 192] << 16), a0);
            a1 = fmaf(sc[t + 1], __uint_as_float((uint)colp[(size_t)(t + 1) * 192] << 16), a1);
            a2 = fmaf(sc[t + 2], __uint_as_float((uint)colp[(size_t)(t + 2) * 192] << 16), a2);
            a3 = fmaf(sc[t + 3], __uint_as_float((uint)colp[(size_t)(t + 3) * 192] << 16), a3);
        }
        for (; t < L; t++)
            a0 = fmaf(sc[t], __uint_as_float((uint)colp[(size_t)t * 192] << 16), a0);
        cn[tid] = ((a0 + a1) + (a2 + a3)) * inv;
    }
    __syncthreads();
    // vec (in smem)
    if (tid < 128) {
        float acc = Wc_b[tid];
        const float* r = Wc_w + (size_t)tid * 140;
        for (int d = 0; d < 140; d++) acc = fmaf(r[d], cn[d], acc);
        vs[tid] = acc;
    } else {
        int jj = tid - 128;
        float acc = Whs_b[jj];
        const float* r = Whs_w + (size_t)jj * 132;
        for (int d = 0; d < 132; d++) acc = fmaf(r[d], q[d], acc);
        vs[128 + jj] = acc;
    }
    if (tid < 128) {
        int op = (w < wn[b]) ? wo[b * 4 + w] : 0;
        vs[256 + tid] = Wop_b[tid] + Wop_w[tid * 4 + op];
    }
    __syncthreads();
    // vpart = out1_b + out1_w[:, :384] . vs  (in smem)
    if (tid < 128) {
        float acc = out1_b[tid];
        const float* r = out1_w + (size_t)tid * 524;
        float a0 = 0.f, a1 = 0.f, a2 = 0.f, a3 = 0.f;
        #pragma unroll 4
        for (int d = 0; d < 384; d += 4) {
            a0 = fmaf(r[d + 0], vs[d + 0], a0);
            a1 = fmaf(r[d + 1], vs[d + 1], a1);
            a2 = fmaf(r[d + 2], vs[d + 2], a2);
            a3 = fmaf(r[d + 3], vs[d + 3], a3);
        }
        vp[tid] = acc + (a0 + a1) + (a2 + a3);
    }
    __syncthreads();
    // final rows: out[b,w,t,:] = tanh(vp + npart[b,t]) @ out2.T + out2_b (masked)
    const float b0 = out2_b[0], b1 = out2_b[1];
    #pragma unroll
    for (int half = 0; half < 2; half++) {
        int t = tid + half * 256;
        float s0, s1;
        if (t < L) {
            s0 = b0; s1 = b1;
            const float4* np4 = (const float4*)(npart + ((size_t)b * 512 + t) * 128);
            for (int h4 = 0; h4 < 32; h4++) {
                float4 n = np4[h4];
                const float* nf = (const float*)&n;
                #pragma unroll
                for (int e = 0; e < 4; e++) {
                    int h = h4 * 4 + e;
                    float z = fast_tanh(vp[h] + nf[e]);
                    s0 = fmaf(z, w2[h], s0);
                    s1 = fmaf(z, w2[128 + h], s1);
                }
            }
        } else {
            s0 = NEGV; s1 = NEGV;
        }
        size_t o = (((size_t)b * 4 + w) * 512 + t) * 2;
        out[o + 0] = s0;
        out[o + 1] = s1;
    }
}

// ---------------------------------------------------------------------------
extern "C" void kernel_launch(void* const* d_in, const int* in_sizes, int n_in,
                              void* d_out, int out_size, void* d_ws, size_t ws_size,
                              hipStream_t stream)
{
    const float* wemb_n   = (const float*)d_in[0];
    const float* wemb_hpu = (const float*)d_in[1];
    const float* Wih_n0f = (const float*)d_in[2];
    const float* Whh_n0f = (const float*)d_in[3];
    const float* b_n0f   = (const float*)d_in[4];
    const float* Wih_n0b = (const float*)d_in[5];
    const float* Whh_n0b = (const float*)d_in[6];
    const float* b_n0b   = (const float*)d_in[7];
    const float* Wih_n1f = (const float*)d_in[8];
    const float* Whh_n1f = (const float*)d_in[9];
    const float* b_n1f   = (const float*)d_in[10];
    const float* Wih_n1b = (const float*)d_in[11];
    const float* Whh_n1b = (const float*)d_in[12];
    const float* b_n1b   = (const float*)d_in[13];
    const float* Wih_h0f = (const float*)d_in[14];
    const float* Whh_h0f = (const float*)d_in[15];
    const float* b_h0f   = (const float*)d_in[16];
    const float* Wih_h0b = (const float*)d_in[17];
    const float* Whh_h0b = (const float*)d_in[18];
    const float* b_h0b   = (const float*)d_in[19];
    const float* Wih_h1f = (const float*)d_in[20];
    const float* Whh_h1f = (const float*)d_in[21];
    const float* b_h1f   = (const float*)d_in[22];
    const float* Wih_h1b = (const float*)d_in[23];
    const float* Whh_h1b = (const float*)d_in[24];
    const float* b_h1b   = (const float*)d_in[25];
    const float* Watt_w  = (const float*)d_in[26];
    const float* Watt_b  = (const float*)d_in[27];
    const float* Wc_w    = (const float*)d_in[28];
    const float* Wc_b    = (const float*)d_in[29];
    const float* Whs_w   = (const float*)d_in[30];
    const float* Whs_b   = (const float*)d_in[31];
    const float* Wop_w   = (const float*)d_in[32];
    const float* Wop_b   = (const float*)d_in[33];
    const float* out1_w  = (const float*)d_in[34];
    const float* out1_b  = (const float*)d_in[35];
    const float* out2_w  = (const float*)d_in[36];
    const float* out2_b  = (const float*)d_in[37];
    const int* l_n   = (const int*)d_in[38];
    const int* l_hpu = (const int*)d_in[39];
    const int* wc    = (const int*)d_in[40];
    const int* wn    = (const int*)d_in[41];
    const int* wo    = (const int*)d_in[42];
    const int* knowledge        = (const int*)d_in[43];
    const int* knowledge_header = (const int*)d_in[44];

    float* ws = (float*)d_ws;
    // ---- workspace map (float offsets; lifetimes annotated) ----
    ushort* proj_q  = (ushort*)(ws + 0);          // [0,12582912)  49152x512 bf16
    ushort* proj_h  = (ushort*)(ws + 12582912);   // [12582912,15728640) 12288x512 bf16
    ushort* AbfH0   = (ushort*)(ws + 15728640);   // wemb_hpu bf16 (dead after G0)
    ushort* A_pad   = (ushort*)(ws + 15728640);   // [49152][192] bf16 (written post-G0)
    ushort* Bp_att  = (ushort*)(ws + 20447232);   // 256x192
    ushort* Bp_out  = (ushort*)(ws + 20471808);   // 128x192
    float*  bias_pad = ws + 20484096;             // 256
    ushort* h_h0_bf = (ushort*)(ws + 22057216);   // 12288x128 bf16
    ushort* WbfQ0   = (ushort*)(ws + 22843648);   // 512x512 bf16
    ushort* WbfH0   = (ushort*)(ws + 22974720);
    ushort* WbfQ1   = (ushort*)(ws + 23105792);   // 512x128
    ushort* WbfH1   = (ushort*)(ws + 23138560);
    uint*   frag8   = (uint*)(ws + 23171328);     // 8 x 4096 dwords int8 Whh (LDS-tiled)
    float*  ksc     = ws + 23204096;              // 8 x 256 scales
    float*  bias_all = ws + 23236864;             // [4][512]
    ushort* AbfQ0   = (ushort*)(ws + 25165824);   // wemb_n bf16 (dead after G0)
    float*  h1_head = ws + 26738688;              // 12288x128 fp32 (post-G0)
    ushort* wenc0_bf = (ushort*)(ws + 31457280);  // 49152x128 bf16 (post-G0)
    float*  attx    = ws + 0;                     // reuse proj_q after QS1
    float*  npart   = ws + 6488064;               // [6488064,12779520)
    float*  outp    = (float*)d_out;

    dim3 blk(256);

    // ---- prep + single fused cast (10 segments, one dispatch) ----
    prep_all_kernel<<<dim3(401), blk, 0, stream>>>(
        Whh_n0f, Whh_n0b, Whh_n1f, Whh_n1b, Whh_h0f, Whh_h0b, Whh_h1f, Whh_h1b,
        frag8, ksc,
        b_n0f, b_n0b, b_n1f, b_n1b, b_h0f, b_h0b, b_h1f, b_h1b, bias_all,
        Watt_w, Bp_att, out1_w, Bp_out, Watt_b, bias_pad);
    cast_multi_kernel<<<dim3(15680), blk, 0, stream>>>(
        wemb_n,   AbfQ0,              25165824,
        wemb_hpu, AbfH0,              6291456,
        Wih_n0f,  WbfQ0,              131072,
        Wih_n0b,  WbfQ0 + 131072,     131072,
        Wih_h0f,  WbfH0,              131072,
        Wih_h0b,  WbfH0 + 131072,     131072,
        Wih_n1f,  WbfQ1,              32768,
        Wih_n1b,  WbfQ1 + 32768,      32768,
        Wih_h1f,  WbfH1,              32768,
        Wih_h1b,  WbfH1 + 32768,      32768);

    // ---- layer 0 projections (QG0 + HG0 in one dispatch) ----
    gemm_dual_kernel<<<dim3(4, 480), blk, 0, stream>>>(
        AbfQ0, WbfQ0, bias_all + 0 * 512, proj_q, 384,
        AbfH0, WbfH0, bias_all + 2 * 512, proj_h,
        512, 512, 512, 2);
    onehot_pad_kernel<<<dim3(192), blk, 0, stream>>>(knowledge, A_pad);

    // ---- layer-0 scans: QS0 || HS0 fused ----
    scan_fused_kernel<1, 1><<<dim3(96 + 1536, 2), dim3(64), 0, stream>>>(
        96,
        proj_q, frag8 + 0 * 4096, frag8 + 1 * 4096, ksc + 0 * 256, ksc + 1 * 256,
        l_n, wenc0_bf, 512, 128,
        proj_h, frag8 + 4 * 4096, frag8 + 5 * 4096, ksc + 4 * 256, ksc + 5 * 256,
        l_hpu, h_h0_bf, 8, 128);

    // ---- layer 1 projections (QG1 + HG1 in one dispatch) ----
    gemm_dual_kernel<<<dim3(4, 480), blk, 0, stream>>>(
        wenc0_bf, WbfQ1, bias_all + 1 * 512, proj_q, 384,
        h_h0_bf, WbfH1, bias_all + 3 * 512, proj_h,
        128, 512, 512, 2);

    // ---- layer-1 scans: QS1 (A_pad bf16, stride 192) || HS1 (fp32) fused ----
    scan_fused_kernel<1, 0><<<dim3(96 + 1536, 2), dim3(64), 0, stream>>>(
        96,
        proj_q, frag8 + 2 * 4096, frag8 + 3 * 4096, ksc + 2 * 256, ksc + 3 * 256,
        l_n, A_pad, 512, 192,
        proj_h, frag8 + 6 * 4096, frag8 + 7 * 4096, ksc + 6 * 256, ksc + 7 * 256,
        l_hpu, h1_head, 8, 128);

    // ---- tail: attx+npart GEMM, then one mega-kernel for everything else ----
    gemm_pair_kernel<<<dim3(3, 384), blk, 0, stream>>>(
        A_pad, Bp_att, bias_pad, attx, Bp_out, npart, 192);
    att_final_kernel<<<dim3(96, 4), blk, 0, stream>>>(
        attx, h1_head, l_hpu, knowledge_header, wc, wn, A_pad, l_n,
        Wc_w, Wc_b, Whs_w, Whs_b, Wop_w, Wop_b, wo,
        out1_w, out1_b, npart, out2_w, out2_b, outp);
}